// Round 6
// baseline (4065.321 us; speedup 1.0000x reference)
//
#include <hip/hip_runtime.h>

#define DI __device__ __forceinline__

typedef unsigned short u16;
typedef unsigned int u32;
typedef unsigned long long u64;
typedef __bf16 bf16v __attribute__((ext_vector_type(8)));   // 8 bf16 = 4 VGPRs (MFMA A/B frag)
typedef float f32x4 __attribute__((ext_vector_type(4)));     // MFMA C/D frag

constexpr int B_ = 256, T_ = 2048, H_ = 128;
constexpr int BU = B_ * 32;        // 8192

// ---- bf16 weight pool offsets (elements) ----
constexpr size_t O_PU_W1 = 0;        // [128][32]
constexpr size_t O_PU_W2 = 4096;     // [128][128]
constexpr size_t O_DY_W1 = 20480;    // [128][256]
constexpr size_t O_DY_W2 = 53248;    // [128][128]
constexpr size_t O_XM_W  = 69632;    // [64][128]
constexpr size_t O_XLV_W = 77824;    // [64][128]
constexpr size_t O_PX_W1 = 86016;    // [128][128]
constexpr size_t O_PX_W2 = 102400;   // [128][128]
constexpr size_t O_ME_W1 = 118784;   // [128][128]
constexpr size_t O_ME_W2 = 135168;   // [32][128]
constexpr size_t O_WIH   = 139264;   // [2][384][128]
constexpr size_t O_WHH   = 237568;   // [2][384][128]

constexpr size_t WS_WB   = 0;
constexpr size_t WS_HST  = 0x100000;
constexpr size_t WS_PART = 0x140000;
constexpr size_t WS_DATA = 0x180000;

DI u16 f2b(float x) {
  union { float f; unsigned u; } v; v.f = x;
  unsigned r = v.u + 0x7fffu + ((v.u >> 16) & 1u);   // RNE
  return (u16)(r >> 16);
}
DI float b2f(u16 h) { union { unsigned u; float f; } v; v.u = ((unsigned)h) << 16; return v.f; }
DI float asf(u32 u) { union { unsigned u; float f; } v; v.u = u; return v.f; }
DI float sigm(float x) {
  return __builtin_amdgcn_rcpf(1.f + __builtin_amdgcn_exp2f(-1.44269504f * x));
}
DI float tanhg(float x) {
  return fmaf(2.f, __builtin_amdgcn_rcpf(1.f + __builtin_amdgcn_exp2f(-2.88539008f * x)), -1.f);
}
DI f32x4 MFMA(bf16v a, bf16v b, f32x4 c) {
  return __builtin_amdgcn_mfma_f32_16x16x32_bf16(a, b, c, 0, 0, 0);
}
DI bf16v ldb(const u16* p) { return *reinterpret_cast<const bf16v*>(p); }
DI u32 cvtpk(float a, float b) {      // [lo]=bf16(a) [hi]=bf16(b), RNE
  u32 d;
  asm("v_cvt_pk_bf16_f32 %0, %1, %2" : "=v"(d) : "v"(a), "v"(b));
  return d;
}
DI u64 pk4(float a, float b, float c, float d) {
  return (u64)cvtpk(a, b) | ((u64)cvtpk(c, d) << 32);
}

// ============ kernel 1: convert weights f32 -> bf16 pool, init h state ============
__global__ void k_convert_weights(
    const float* pu_w1, const float* pu_w2, const float* dy_w1, const float* dy_w2,
    const float* xm_w, const float* xlv_w, const float* px_w1, const float* px_w2,
    const float* me_w1, const float* me_w2, const float* gih, const float* ghh,
    const float* h0, u16* wb, float* hst) {
  int i0 = blockIdx.x * blockDim.x + threadIdx.x;
  int st = gridDim.x * blockDim.x;
#define CVT(src, off, n) for (int i = i0; i < (n); i += st) wb[(off) + i] = f2b(src[i]);
  CVT(pu_w1, O_PU_W1, 4096)  CVT(pu_w2, O_PU_W2, 16384)
  CVT(dy_w1, O_DY_W1, 32768) CVT(dy_w2, O_DY_W2, 16384)
  CVT(xm_w,  O_XM_W,  8192)  CVT(xlv_w, O_XLV_W, 8192)
  CVT(px_w1, O_PX_W1, 16384) CVT(px_w2, O_PX_W2, 16384)
  CVT(me_w1, O_ME_W1, 16384) CVT(me_w2, O_ME_W2, 4096)
  CVT(gih,   O_WIH,   98304) CVT(ghh,   O_WHH,   98304)
#undef CVT
  for (int i = i0; i < 2 * B_ * H_; i += st) hst[i] = h0[i];
}

// ============ kernel 2: transpose u,y slice: [BU][T] f32 -> [TC][BU] bf16 ============
__global__ void k_transpose(const float* __restrict__ u, const float* __restrict__ y,
                            u16* __restrict__ uT, u16* __restrict__ yT, int t0) {
  const float* src = blockIdx.z ? y : u;
  u16* dst = blockIdx.z ? yT : uT;
  __shared__ float tile[32][33];
  const int tx = threadIdx.x, ty = threadIdx.y;      // 32 x 8
  const int c0 = blockIdx.x * 32;
  const int r0 = blockIdx.y * 32;
#pragma unroll
  for (int i = 0; i < 4; ++i)
    tile[ty + i * 8][tx] = src[(size_t)(r0 + ty + i * 8) * T_ + t0 + c0 + tx];
  __syncthreads();
#pragma unroll
  for (int i = 0; i < 4; ++i)
    dst[(size_t)(c0 + ty + i * 8) * BU + r0 + tx] = f2b(tile[tx][ty + i * 8]);
}

// ============ kernel 3: phi_u + gi0 for one chunk ============
// Per wave: 32 rows. Computes phi_u (2-layer MLP) into LDS, writes phiu
// (coalesced), then gi0 = phi_u @ Wih0^T (swapped-operand MFMA) -> global bf16.
__global__ __launch_bounds__(256) void k_phi_u(
    const u16* __restrict__ uT, const u16* __restrict__ wb,
    const float* __restrict__ pu_b1, const float* __restrict__ pu_b2,
    u16* __restrict__ phiu, u16* __restrict__ gi0) {
  __shared__ __align__(16) u16 hid[4][32 * 136];
  __shared__ __align__(16) u16 ph[4][32 * 136];
  const int lane = threadIdx.x & 63, w = threadIdx.x >> 6;
  const int ln = lane & 15, lq = lane >> 4;
  const int r0 = (blockIdx.x * 4 + w) * 32;
  u16* hb = hid[w];
  u16* hb2 = ph[w];

  // layer 1: K=32, out 128, relu
  bf16v a0 = ldb(uT + (size_t)(r0 + ln) * 32 + lq * 8);
  bf16v a1 = ldb(uT + (size_t)(r0 + 16 + ln) * 32 + lq * 8);
  const u16* w1 = wb + O_PU_W1;
#pragma unroll
  for (int nt = 0; nt < 8; ++nt) {
    f32x4 c0 = {0.f, 0.f, 0.f, 0.f}, c1 = {0.f, 0.f, 0.f, 0.f};
    bf16v b = ldb(w1 + (nt * 16 + ln) * 32 + lq * 8);
    c0 = MFMA(a0, b, c0); c1 = MFMA(a1, b, c1);
    float bv = pu_b1[nt * 16 + ln];
#pragma unroll
    for (int j = 0; j < 4; ++j) {
      hb[(lq * 4 + j) * 136 + nt * 16 + ln]      = f2b(fmaxf(c0[j] + bv, 0.f));
      hb[(16 + lq * 4 + j) * 136 + nt * 16 + ln] = f2b(fmaxf(c1[j] + bv, 0.f));
    }
  }
  // layer 2: K=128, out 128 -> LDS hb2
  bf16v a[2][4];
#pragma unroll
  for (int mt = 0; mt < 2; ++mt)
#pragma unroll
    for (int kt = 0; kt < 4; ++kt)
      a[mt][kt] = ldb(hb + (mt * 16 + ln) * 136 + kt * 32 + lq * 8);
  const u16* w2 = wb + O_PU_W2;
#pragma unroll
  for (int nt = 0; nt < 8; ++nt) {
    f32x4 c0 = {0.f, 0.f, 0.f, 0.f}, c1 = {0.f, 0.f, 0.f, 0.f};
#pragma unroll
    for (int kt = 0; kt < 4; ++kt) {
      bf16v b = ldb(w2 + (nt * 16 + ln) * 128 + kt * 32 + lq * 8);
      c0 = MFMA(a[0][kt], b, c0); c1 = MFMA(a[1][kt], b, c1);
    }
    float bv = pu_b2[nt * 16 + ln];
#pragma unroll
    for (int mt = 0; mt < 2; ++mt)
#pragma unroll
      for (int j = 0; j < 4; ++j) {
        float v = (mt ? c1[j] : c0[j]) + bv;
        hb2[(mt * 16 + lq * 4 + j) * 136 + nt * 16 + ln] = f2b(v);
      }
  }
  __syncthreads();

  // coalesced copy hb2 -> phiu global (16 u64 / lane)
#pragma unroll
  for (int i = 0; i < 16; ++i) {
    int idx = lane + 64 * i;               // u64 index in 32x128 tile
    int row = idx >> 5, c4 = idx & 31;
    u64 v = *reinterpret_cast<const u64*>(&hb2[row * 136 + c4 * 4]);
    *reinterpret_cast<u64*>(&phiu[(size_t)(r0 + row) * 128 + c4 * 4]) = v;
  }

  // gi0 = phi_u @ Wih0^T  (swapped operands: D rows = gate-features, cols = batch)
  bf16v bP[2][4];
#pragma unroll
  for (int bh = 0; bh < 2; ++bh)
#pragma unroll
    for (int kt = 0; kt < 4; ++kt)
      bP[bh][kt] = ldb(&hb2[(bh * 16 + ln) * 136 + kt * 32 + lq * 8]);
  const u16* wih0 = wb + O_WIH;
  for (int nt = 0; nt < 24; ++nt) {
    bf16v aW[4];
#pragma unroll
    for (int kt = 0; kt < 4; ++kt)
      aW[kt] = ldb(wih0 + (size_t)(nt * 16 + ln) * 128 + kt * 32 + lq * 8);
#pragma unroll
    for (int bh = 0; bh < 2; ++bh) {
      f32x4 c = {0.f, 0.f, 0.f, 0.f};
#pragma unroll
      for (int kt = 0; kt < 4; ++kt) c = MFMA(aW[kt], bP[bh][kt], c);
      u64 q = pk4(c[0], c[1], c[2], c[3]);
      *reinterpret_cast<u64*>(
          &gi0[(size_t)(r0 + bh * 16 + ln) * 384 + nt * 16 + lq * 4]) = q;
    }
  }
}

// ============ kernel 4: sequential 2-layer GRU over one chunk, 16 WGs ============
// gi0 precomputed -> only 36 weight frags (144 VGPR) live; everything fits in
// the 256-VGPR budget so weights stay register-resident without pinning.
__global__ __launch_bounds__(512, 2) void k_gru_seq(
    const u16* __restrict__ gi0, const u16* __restrict__ wb,
    float* __restrict__ hst, u16* __restrict__ h1old, int TCr) {
  __shared__ __align__(16) u16 H0[2][16 * 136];
  __shared__ __align__(16) u16 H1[2][16 * 136];
  const int lane = threadIdx.x & 63, w = threadIdx.x >> 6;   // 8 waves
  const int ln = lane & 15, lq = lane >> 4;
  const int f0 = w * 16;
  const int fme = f0 + lq * 4;
  const int b0 = blockIdx.x * 16;
  const u16* wh0 = wb + O_WHH;
  const u16* wi1 = wb + O_WIH + 49152;
  const u16* wh1 = wb + O_WHH + 49152;

  // 36 loop-invariant weight frags (144 VGPR)
  bf16v wH0[3][4], wI1[3][4], wH1[3][4];
#pragma unroll
  for (int g = 0; g < 3; ++g)
#pragma unroll
    for (int kt = 0; kt < 4; ++kt) {
      size_t row = (size_t)(g * 128 + f0 + ln);
      size_t col = (size_t)kt * 32 + lq * 8;
      wH0[g][kt] = ldb(wh0 + row * H_ + col);
      wI1[g][kt] = ldb(wi1 + row * H_ + col);
      wH1[g][kt] = ldb(wh1 + row * H_ + col);
    }

  float h0s[4], h1s[4];
#pragma unroll
  for (int j = 0; j < 4; ++j) {
    h0s[j] = hst[(size_t)(0 * B_ + b0 + ln) * H_ + fme + j];
    h1s[j] = hst[(size_t)(1 * B_ + b0 + ln) * H_ + fme + j];
  }
  *reinterpret_cast<u64*>(&H0[0][ln * 136 + fme]) = pk4(h0s[0], h0s[1], h0s[2], h0s[3]);
  *reinterpret_cast<u64*>(&H1[0][ln * 136 + fme]) = pk4(h1s[0], h1s[1], h1s[2], h1s[3]);
  u16* hp = h1old + (size_t)(b0 + ln) * H_ + fme;
  *reinterpret_cast<u64*>(hp) = pk4(h1s[0], h1s[1], h1s[2], h1s[3]);   // t=0 slot

  // gi0 base for this thread; advances by B*384 elements per step
  const u16* gp = gi0 + (size_t)(b0 + ln) * 384 + fme;
  u64 gq0 = *reinterpret_cast<const u64*>(gp);          // gate r
  u64 gq1 = *reinterpret_cast<const u64*>(gp + 128);    // gate z
  u64 gq2 = *reinterpret_cast<const u64*>(gp + 256);    // gate n
  gp += (size_t)B_ * 384;

  __syncthreads();

#define GRU_STEP(CUR, NXT, T)                                                   \
  {                                                                             \
    /* ---- layer 0: h-side MFMA + precomputed gi0 ---- */                      \
    f32x4 cR = {0,0,0,0}, cZ = {0,0,0,0}, cHN = {0,0,0,0};                      \
    _Pragma("unroll")                                                           \
    for (int kt = 0; kt < 4; ++kt) {                                            \
      bf16v aH = ldb(&H0[CUR][ln * 136 + kt * 32 + lq * 8]);                    \
      cR  = MFMA(wH0[0][kt], aH, cR);                                           \
      cZ  = MFMA(wH0[1][kt], aH, cZ);                                           \
      cHN = MFMA(wH0[2][kt], aH, cHN);                                          \
    }                                                                           \
    {                                                                           \
      u32 l0 = (u32)gq0, h0w = (u32)(gq0 >> 32);                                \
      u32 l1 = (u32)gq1, h1w = (u32)(gq1 >> 32);                                \
      u32 l2 = (u32)gq2, h2w = (u32)(gq2 >> 32);                                \
      float gr[4] = {asf(l0 << 16), asf(l0 & 0xffff0000u),                      \
                     asf(h0w << 16), asf(h0w & 0xffff0000u)};                   \
      float gz[4] = {asf(l1 << 16), asf(l1 & 0xffff0000u),                      \
                     asf(h1w << 16), asf(h1w & 0xffff0000u)};                   \
      float gn[4] = {asf(l2 << 16), asf(l2 & 0xffff0000u),                      \
                     asf(h2w << 16), asf(h2w & 0xffff0000u)};                   \
      _Pragma("unroll")                                                         \
      for (int j = 0; j < 4; ++j) {                                             \
        float r = sigm(cR[j] + gr[j]);                                          \
        float z = sigm(cZ[j] + gz[j]);                                          \
        float n = tanhg(fmaf(r, cHN[j], gn[j]));                                \
        h0s[j] = fmaf(z, h0s[j] - n, n);                                        \
      }                                                                         \
      *reinterpret_cast<u64*>(&H0[NXT][ln * 136 + fme]) =                       \
          pk4(h0s[0], h0s[1], h0s[2], h0s[3]);                                  \
    }                                                                           \
    __syncthreads();                                                            \
    /* prefetch gi0 for t+1 (post-barrier; consumed next step pre-barrier) */   \
    if ((T) + 1 < TCr) {                                                        \
      gq0 = *reinterpret_cast<const u64*>(gp);                                  \
      gq1 = *reinterpret_cast<const u64*>(gp + 128);                            \
      gq2 = *reinterpret_cast<const u64*>(gp + 256);                            \
      gp += (size_t)B_ * 384;                                                   \
    }                                                                           \
    /* ---- layer 1 ---- */                                                     \
    f32x4 dR = {0,0,0,0}, dZ = {0,0,0,0}, dIN = {0,0,0,0}, dHN = {0,0,0,0};     \
    _Pragma("unroll")                                                           \
    for (int kt = 0; kt < 4; ++kt) {                                            \
      bf16v aI  = ldb(&H0[NXT][ln * 136 + kt * 32 + lq * 8]);                   \
      bf16v aH1 = ldb(&H1[CUR][ln * 136 + kt * 32 + lq * 8]);                   \
      dR  = MFMA(wI1[0][kt], aI,  dR);                                          \
      dR  = MFMA(wH1[0][kt], aH1, dR);                                          \
      dZ  = MFMA(wI1[1][kt], aI,  dZ);                                          \
      dZ  = MFMA(wH1[1][kt], aH1, dZ);                                          \
      dIN = MFMA(wI1[2][kt], aI,  dIN);                                         \
      dHN = MFMA(wH1[2][kt], aH1, dHN);                                         \
    }                                                                           \
    {                                                                           \
      _Pragma("unroll")                                                         \
      for (int j = 0; j < 4; ++j) {                                             \
        float r = sigm(dR[j]);                                                  \
        float z = sigm(dZ[j]);                                                  \
        float n = tanhg(fmaf(r, dHN[j], dIN[j]));                               \
        h1s[j] = fmaf(z, h1s[j] - n, n);                                        \
      }                                                                         \
      u64 q = pk4(h1s[0], h1s[1], h1s[2], h1s[3]);                              \
      *reinterpret_cast<u64*>(&H1[NXT][ln * 136 + fme]) = q;                    \
      if ((T) + 1 < TCr) {                                                      \
        hp += (size_t)B_ * H_;                                                  \
        *reinterpret_cast<u64*>(hp) = q;                                        \
      }                                                                         \
    }                                                                           \
  }

  for (int tt = 0; tt < TCr; tt += 2) {
    GRU_STEP(0, 1, tt)
    GRU_STEP(1, 0, tt + 1)
  }
#undef GRU_STEP

  // persist h state for next chunk
#pragma unroll
  for (int j = 0; j < 4; ++j) {
    hst[(size_t)(0 * B_ + b0 + ln) * H_ + fme + j] = h0s[j];
    hst[(size_t)(1 * B_ + b0 + ln) * H_ + fme + j] = h1s[j];
  }
}

// ============ kernel 5: post-chain + loss partials (one chunk) ============
DI void layer128(const u16* __restrict__ W, const float* __restrict__ bias,
                 const u16* A, u16* Dst, int dstOff, int nTiles, bool relu,
                 int ln, int lq) {
  bf16v a[2][4];
#pragma unroll
  for (int mt = 0; mt < 2; ++mt)
#pragma unroll
    for (int kt = 0; kt < 4; ++kt)
      a[mt][kt] = ldb(A + (mt * 16 + ln) * 136 + kt * 32 + lq * 8);
  for (int nt = 0; nt < nTiles; ++nt) {
    f32x4 c0 = {0,0,0,0}, c1 = {0,0,0,0};
#pragma unroll
    for (int kt = 0; kt < 4; ++kt) {
      bf16v b = ldb(W + (nt * 16 + ln) * 128 + kt * 32 + lq * 8);
      c0 = MFMA(a[0][kt], b, c0); c1 = MFMA(a[1][kt], b, c1);
    }
    float bv = bias[nt * 16 + ln];
#pragma unroll
    for (int mt = 0; mt < 2; ++mt)
#pragma unroll
      for (int j = 0; j < 4; ++j) {
        float v = (mt ? c1[j] : c0[j]) + bv;
        if (relu) v = fmaxf(v, 0.f);
        Dst[(mt * 16 + lq * 4 + j) * 136 + dstOff + nt * 16 + ln] = f2b(v);
      }
  }
}

__global__ __launch_bounds__(128) void k_post(
    const u16* __restrict__ phiu, const u16* __restrict__ h1old,
    const u16* __restrict__ yT, const u16* __restrict__ wb,
    const float* __restrict__ dy_b1, const float* __restrict__ dy_b2,
    const float* __restrict__ xm_b, const float* __restrict__ xlv_b,
    const float* __restrict__ px_b1, const float* __restrict__ px_b2,
    const float* __restrict__ me_b1, const float* __restrict__ me_b2,
    float* __restrict__ partials, int first) {
  __shared__ __align__(16) u16 buf[2][2][32 * 136];
  __shared__ float wsum[2];
  const int lane = threadIdx.x & 63, w = threadIdx.x >> 6;   // 2 waves
  const int ln = lane & 15, lq = lane >> 4;
  const int r0 = (blockIdx.x * 2 + w) * 32;
  u16* X = buf[w][0];
  u16* Yb = buf[w][1];

  {
    bf16v a[2][8];
#pragma unroll
    for (int mt = 0; mt < 2; ++mt)
#pragma unroll
      for (int kt = 0; kt < 8; ++kt) {
        size_t row = (size_t)(r0 + mt * 16 + ln);
        a[mt][kt] = (kt < 4) ? ldb(phiu + row * H_ + kt * 32 + lq * 8)
                             : ldb(h1old + row * H_ + (kt - 4) * 32 + lq * 8);
      }
    const u16* W = wb + O_DY_W1;
    for (int nt = 0; nt < 8; ++nt) {
      f32x4 c0 = {0,0,0,0}, c1 = {0,0,0,0};
#pragma unroll
      for (int kt = 0; kt < 8; ++kt) {
        bf16v b = ldb(W + (nt * 16 + ln) * 256 + kt * 32 + lq * 8);
        c0 = MFMA(a[0][kt], b, c0); c1 = MFMA(a[1][kt], b, c1);
      }
      float bv = dy_b1[nt * 16 + ln];
#pragma unroll
      for (int mt = 0; mt < 2; ++mt)
#pragma unroll
        for (int j = 0; j < 4; ++j) {
          float v = (mt ? c1[j] : c0[j]) + bv;
          X[(mt * 16 + lq * 4 + j) * 136 + nt * 16 + ln] = f2b(fmaxf(v, 0.f));
        }
    }
  }
  layer128(wb + O_DY_W2, dy_b2, X, Yb, 0, 8, false, ln, lq);
  layer128(wb + O_XM_W,  xm_b,  Yb, X, 0, 4, false, ln, lq);
  layer128(wb + O_XLV_W, xlv_b, Yb, X, 64, 4, false, ln, lq);
  layer128(wb + O_PX_W1, px_b1, X, Yb, 0, 8, true,  ln, lq);
  layer128(wb + O_PX_W2, px_b2, Yb, X, 0, 8, false, ln, lq);
  layer128(wb + O_ME_W1, me_b1, X, Yb, 0, 8, true,  ln, lq);

  float lsum = 0.f;
  {
    bf16v a[2][4];
#pragma unroll
    for (int mt = 0; mt < 2; ++mt)
#pragma unroll
      for (int kt = 0; kt < 4; ++kt)
        a[mt][kt] = ldb(Yb + (mt * 16 + ln) * 136 + kt * 32 + lq * 8);
    const u16* W = wb + O_ME_W2;
#pragma unroll
    for (int nt = 0; nt < 2; ++nt) {
      f32x4 c0 = {0,0,0,0}, c1 = {0,0,0,0};
#pragma unroll
      for (int kt = 0; kt < 4; ++kt) {
        bf16v b = ldb(W + (nt * 16 + ln) * 128 + kt * 32 + lq * 8);
        c0 = MFMA(a[0][kt], b, c0); c1 = MFMA(a[1][kt], b, c1);
      }
      float bv = me_b2[nt * 16 + ln];
#pragma unroll
      for (int mt = 0; mt < 2; ++mt)
#pragma unroll
        for (int j = 0; j < 4; ++j) {
          int m = mt * 16 + lq * 4 + j;
          float v = (mt ? c1[j] : c0[j]) + bv;
          float yv = b2f(yT[(size_t)(r0 + m) * 32 + nt * 16 + ln]);
          float d = v - yv;
          lsum += d * d;
        }
    }
  }
#pragma unroll
  for (int o = 32; o; o >>= 1) lsum += __shfl_down(lsum, o);
  if (lane == 0) wsum[w] = lsum;
  __syncthreads();
  if (threadIdx.x == 0) {
    float v = wsum[0] + wsum[1];
    if (first) partials[blockIdx.x] = v;
    else       partials[blockIdx.x] += v;
  }
}

// ============ kernel 6: deterministic final reduction ============
__global__ void k_finalize(const float* __restrict__ partials, float* __restrict__ out,
                           int nPart) {
  __shared__ double s[256];
  double acc = 0.0;
  for (int i = threadIdx.x; i < nPart; i += 256) acc += (double)partials[i];
  s[threadIdx.x] = acc;
  __syncthreads();
  for (int o = 128; o; o >>= 1) {
    if (threadIdx.x < o) s[threadIdx.x] += s[threadIdx.x + o];
    __syncthreads();
  }
  if (threadIdx.x == 0) out[0] = (float)s[0];
}

extern "C" void kernel_launch(void* const* d_in, const int* in_sizes, int n_in,
                              void* d_out, int out_size, void* d_ws, size_t ws_size,
                              hipStream_t stream) {
  const float* u     = (const float*)d_in[0];
  const float* y     = (const float*)d_in[1];
  const float* h0    = (const float*)d_in[2];
  const float* pu_w1 = (const float*)d_in[3];
  const float* pu_b1 = (const float*)d_in[4];
  const float* pu_w2 = (const float*)d_in[5];
  const float* pu_b2 = (const float*)d_in[6];
  const float* dy_w1 = (const float*)d_in[7];
  const float* dy_b1 = (const float*)d_in[8];
  const float* dy_w2 = (const float*)d_in[9];
  const float* dy_b2 = (const float*)d_in[10];
  const float* xm_w  = (const float*)d_in[11];
  const float* xm_b  = (const float*)d_in[12];
  const float* xlv_w = (const float*)d_in[13];
  const float* xlv_b = (const float*)d_in[14];
  const float* px_w1 = (const float*)d_in[15];
  const float* px_b1 = (const float*)d_in[16];
  const float* px_w2 = (const float*)d_in[17];
  const float* px_b2 = (const float*)d_in[18];
  const float* me_w1 = (const float*)d_in[19];
  const float* me_b1 = (const float*)d_in[20];
  const float* me_w2 = (const float*)d_in[21];
  const float* me_b2 = (const float*)d_in[22];
  const float* gih   = (const float*)d_in[23];
  const float* ghh   = (const float*)d_in[24];

  // runtime time-chunk tier vs workspace size
  int TC = 64;
  for (int cand : {256, 128}) {
    size_t ut = (size_t)cand * B_ * 32 * 2;      // uT or yT
    size_t ph = (size_t)cand * B_ * 128 * 2;     // phiu or h1old
    size_t gi = (size_t)cand * B_ * 384 * 2;     // gi0
    if (WS_DATA + 2 * ut + 2 * ph + gi <= ws_size) { TC = cand; break; }
  }
  const int NCH = T_ / TC;
  const int RC = TC * B_;
  size_t ut_b = (size_t)RC * 32 * 2, ph_b = (size_t)RC * 128 * 2;

  char* ws = (char*)d_ws;
  u16* wb    = (u16*)(ws + WS_WB);
  float* hst = (float*)(ws + WS_HST);
  float* prt = (float*)(ws + WS_PART);
  u16* uT    = (u16*)(ws + WS_DATA);
  u16* yT    = (u16*)(ws + WS_DATA + ut_b);
  u16* phiu  = (u16*)(ws + WS_DATA + 2 * ut_b);
  u16* h1o   = (u16*)(ws + WS_DATA + 2 * ut_b + ph_b);
  u16* gi0   = (u16*)(ws + WS_DATA + 2 * ut_b + 2 * ph_b);
  float* out = (float*)d_out;

  k_convert_weights<<<256, 256, 0, stream>>>(pu_w1, pu_w2, dy_w1, dy_w2, xm_w, xlv_w,
                                             px_w1, px_w2, me_w1, me_w2, gih, ghh,
                                             h0, wb, hst);
  for (int c = 0; c < NCH; ++c) {
    k_transpose<<<dim3(TC / 32, 256, 2), dim3(32, 8), 0, stream>>>(u, y, uT, yT, c * TC);
    k_phi_u<<<RC / 128, 256, 0, stream>>>(uT, wb, pu_b1, pu_b2, phiu, gi0);
    k_gru_seq<<<16, 512, 0, stream>>>(gi0, wb, hst, h1o, TC);
    k_post<<<RC / 64, 128, 0, stream>>>(phiu, h1o, yT, wb, dy_b1, dy_b2, xm_b, xlv_b,
                                        px_b1, px_b2, me_b1, me_b2, prt, c == 0 ? 1 : 0);
  }
  k_finalize<<<1, 256, 0, stream>>>(prt, out, RC / 64);
}

// Round 7
// 3678.511 us; speedup vs baseline: 1.1052x; 1.1052x over previous
//
#include <hip/hip_runtime.h>

#define DI __device__ __forceinline__

typedef unsigned short u16;
typedef unsigned int u32;
typedef unsigned long long u64;
typedef __bf16 bf16v __attribute__((ext_vector_type(8)));   // 8 bf16 = 4 VGPRs (MFMA A/B frag)
typedef float f32x4 __attribute__((ext_vector_type(4)));     // MFMA C/D frag

constexpr int B_ = 256, T_ = 2048, H_ = 128;
constexpr int BU = B_ * 32;        // 8192

// ---- bf16 weight pool offsets (elements) ----
constexpr size_t O_PU_W1 = 0;        // [128][32]
constexpr size_t O_PU_W2 = 4096;     // [128][128]
constexpr size_t O_DY_W1 = 20480;    // [128][256]
constexpr size_t O_DY_W2 = 53248;    // [128][128]
constexpr size_t O_XM_W  = 69632;    // [64][128]
constexpr size_t O_XLV_W = 77824;    // [64][128]
constexpr size_t O_PX_W1 = 86016;    // [128][128]
constexpr size_t O_PX_W2 = 102400;   // [128][128]
constexpr size_t O_ME_W1 = 118784;   // [128][128]
constexpr size_t O_ME_W2 = 135168;   // [32][128]
constexpr size_t O_WIH   = 139264;   // [2][384][128]
constexpr size_t O_WHH   = 237568;   // [2][384][128]

constexpr size_t WS_WB   = 0;
constexpr size_t WS_HST  = 0x100000;
constexpr size_t WS_PART = 0x140000;
constexpr size_t WS_DATA = 0x180000;

DI u16 f2b(float x) {
  union { float f; unsigned u; } v; v.f = x;
  unsigned r = v.u + 0x7fffu + ((v.u >> 16) & 1u);   // RNE
  return (u16)(r >> 16);
}
DI float b2f(u16 h) { union { unsigned u; float f; } v; v.u = ((unsigned)h) << 16; return v.f; }
DI float asf(u32 u) { union { unsigned u; float f; } v; v.u = u; return v.f; }
DI float sigm(float x) {
  return __builtin_amdgcn_rcpf(1.f + __builtin_amdgcn_exp2f(-1.44269504f * x));
}
DI float tanhg(float x) {
  return fmaf(2.f, __builtin_amdgcn_rcpf(1.f + __builtin_amdgcn_exp2f(-2.88539008f * x)), -1.f);
}
DI f32x4 MFMA(bf16v a, bf16v b, f32x4 c) {
  return __builtin_amdgcn_mfma_f32_16x16x32_bf16(a, b, c, 0, 0, 0);
}
// MFMA with A operand pinned in AGPRs (compiler cannot evict/sink AGPR values)
DI void MFA(f32x4& c, const bf16v& a_agpr, const bf16v& b) {
  asm("v_mfma_f32_16x16x32_bf16 %0, %1, %2, %0"
      : "+v"(c) : "a"(a_agpr), "v"(b));
}
DI bf16v ldb(const u16* p) { return *reinterpret_cast<const bf16v*>(p); }
DI u32 cvtpk(float a, float b) {      // [lo]=bf16(a) [hi]=bf16(b), RNE
  u32 d;
  asm("v_cvt_pk_bf16_f32 %0, %1, %2" : "=v"(d) : "v"(a), "v"(b));
  return d;
}
DI u64 pk4(float a, float b, float c, float d) {
  return (u64)cvtpk(a, b) | ((u64)cvtpk(c, d) << 32);
}

// ============ kernel 1: convert weights f32 -> bf16 pool, init h state ============
__global__ void k_convert_weights(
    const float* pu_w1, const float* pu_w2, const float* dy_w1, const float* dy_w2,
    const float* xm_w, const float* xlv_w, const float* px_w1, const float* px_w2,
    const float* me_w1, const float* me_w2, const float* gih, const float* ghh,
    const float* h0, u16* wb, float* hst) {
  int i0 = blockIdx.x * blockDim.x + threadIdx.x;
  int st = gridDim.x * blockDim.x;
#define CVT(src, off, n) for (int i = i0; i < (n); i += st) wb[(off) + i] = f2b(src[i]);
  CVT(pu_w1, O_PU_W1, 4096)  CVT(pu_w2, O_PU_W2, 16384)
  CVT(dy_w1, O_DY_W1, 32768) CVT(dy_w2, O_DY_W2, 16384)
  CVT(xm_w,  O_XM_W,  8192)  CVT(xlv_w, O_XLV_W, 8192)
  CVT(px_w1, O_PX_W1, 16384) CVT(px_w2, O_PX_W2, 16384)
  CVT(me_w1, O_ME_W1, 16384) CVT(me_w2, O_ME_W2, 4096)
  CVT(gih,   O_WIH,   98304) CVT(ghh,   O_WHH,   98304)
#undef CVT
  for (int i = i0; i < 2 * B_ * H_; i += st) hst[i] = h0[i];
}

// ============ kernel 2: transpose u,y slice: [BU][T] f32 -> [TC][BU] bf16 ============
__global__ void k_transpose(const float* __restrict__ u, const float* __restrict__ y,
                            u16* __restrict__ uT, u16* __restrict__ yT, int t0) {
  const float* src = blockIdx.z ? y : u;
  u16* dst = blockIdx.z ? yT : uT;
  __shared__ float tile[32][33];
  const int tx = threadIdx.x, ty = threadIdx.y;      // 32 x 8
  const int c0 = blockIdx.x * 32;
  const int r0 = blockIdx.y * 32;
#pragma unroll
  for (int i = 0; i < 4; ++i)
    tile[ty + i * 8][tx] = src[(size_t)(r0 + ty + i * 8) * T_ + t0 + c0 + tx];
  __syncthreads();
#pragma unroll
  for (int i = 0; i < 4; ++i)
    dst[(size_t)(c0 + ty + i * 8) * BU + r0 + tx] = f2b(tile[tx][ty + i * 8]);
}

// ============ kernel 3: phi_u + gi0 for one chunk ============
__global__ __launch_bounds__(256) void k_phi_u(
    const u16* __restrict__ uT, const u16* __restrict__ wb,
    const float* __restrict__ pu_b1, const float* __restrict__ pu_b2,
    u16* __restrict__ phiu, u16* __restrict__ gi0) {
  __shared__ __align__(16) u16 hid[4][32 * 136];
  __shared__ __align__(16) u16 ph[4][32 * 136];
  const int lane = threadIdx.x & 63, w = threadIdx.x >> 6;
  const int ln = lane & 15, lq = lane >> 4;
  const int r0 = (blockIdx.x * 4 + w) * 32;
  u16* hb = hid[w];
  u16* hb2 = ph[w];

  // layer 1: K=32, out 128, relu
  bf16v a0 = ldb(uT + (size_t)(r0 + ln) * 32 + lq * 8);
  bf16v a1 = ldb(uT + (size_t)(r0 + 16 + ln) * 32 + lq * 8);
  const u16* w1 = wb + O_PU_W1;
#pragma unroll
  for (int nt = 0; nt < 8; ++nt) {
    f32x4 c0 = {0.f, 0.f, 0.f, 0.f}, c1 = {0.f, 0.f, 0.f, 0.f};
    bf16v b = ldb(w1 + (nt * 16 + ln) * 32 + lq * 8);
    c0 = MFMA(a0, b, c0); c1 = MFMA(a1, b, c1);
    float bv = pu_b1[nt * 16 + ln];
#pragma unroll
    for (int j = 0; j < 4; ++j) {
      hb[(lq * 4 + j) * 136 + nt * 16 + ln]      = f2b(fmaxf(c0[j] + bv, 0.f));
      hb[(16 + lq * 4 + j) * 136 + nt * 16 + ln] = f2b(fmaxf(c1[j] + bv, 0.f));
    }
  }
  // layer 2: K=128, out 128 -> LDS hb2
  bf16v a[2][4];
#pragma unroll
  for (int mt = 0; mt < 2; ++mt)
#pragma unroll
    for (int kt = 0; kt < 4; ++kt)
      a[mt][kt] = ldb(hb + (mt * 16 + ln) * 136 + kt * 32 + lq * 8);
  const u16* w2 = wb + O_PU_W2;
#pragma unroll
  for (int nt = 0; nt < 8; ++nt) {
    f32x4 c0 = {0.f, 0.f, 0.f, 0.f}, c1 = {0.f, 0.f, 0.f, 0.f};
#pragma unroll
    for (int kt = 0; kt < 4; ++kt) {
      bf16v b = ldb(w2 + (nt * 16 + ln) * 128 + kt * 32 + lq * 8);
      c0 = MFMA(a[0][kt], b, c0); c1 = MFMA(a[1][kt], b, c1);
    }
    float bv = pu_b2[nt * 16 + ln];
#pragma unroll
    for (int mt = 0; mt < 2; ++mt)
#pragma unroll
      for (int j = 0; j < 4; ++j) {
        float v = (mt ? c1[j] : c0[j]) + bv;
        hb2[(mt * 16 + lq * 4 + j) * 136 + nt * 16 + ln] = f2b(v);
      }
  }
  __syncthreads();

  // coalesced copy hb2 -> phiu global (16 u64 / lane)
#pragma unroll
  for (int i = 0; i < 16; ++i) {
    int idx = lane + 64 * i;               // u64 index in 32x128 tile
    int row = idx >> 5, c4 = idx & 31;
    u64 v = *reinterpret_cast<const u64*>(&hb2[row * 136 + c4 * 4]);
    *reinterpret_cast<u64*>(&phiu[(size_t)(r0 + row) * 128 + c4 * 4]) = v;
  }

  // gi0 = phi_u @ Wih0^T  (swapped operands: D rows = gate-features, cols = batch)
  bf16v bP[2][4];
#pragma unroll
  for (int bh = 0; bh < 2; ++bh)
#pragma unroll
    for (int kt = 0; kt < 4; ++kt)
      bP[bh][kt] = ldb(&hb2[(bh * 16 + ln) * 136 + kt * 32 + lq * 8]);
  const u16* wih0 = wb + O_WIH;
  for (int nt = 0; nt < 24; ++nt) {
    bf16v aW[4];
#pragma unroll
    for (int kt = 0; kt < 4; ++kt)
      aW[kt] = ldb(wih0 + (size_t)(nt * 16 + ln) * 128 + kt * 32 + lq * 8);
#pragma unroll
    for (int bh = 0; bh < 2; ++bh) {
      f32x4 c = {0.f, 0.f, 0.f, 0.f};
#pragma unroll
      for (int kt = 0; kt < 4; ++kt) c = MFMA(aW[kt], bP[bh][kt], c);
      u64 q = pk4(c[0], c[1], c[2], c[3]);
      *reinterpret_cast<u64*>(
          &gi0[(size_t)(r0 + bh * 16 + ln) * 384 + nt * 16 + lq * 4]) = q;
    }
  }
}

// ============ kernel 4: sequential 2-layer GRU over one chunk, 16 WGs ============
// 36 weight frags pinned in AGPRs (144 AGPR) via "a"-constraint inline asm;
// arch-VGPR live set ~110 -> 254 unified regs/thread, 2 waves/SIMD. The
// register allocator cannot sink AGPR values, so the per-step 288 KB/CU L2
// weight re-fetch (the r4-r6 bottleneck) is eliminated.
__global__ __launch_bounds__(512, 2) void k_gru_seq(
    const u16* __restrict__ gi0, const u16* __restrict__ wb,
    float* __restrict__ hst, u16* __restrict__ h1old, int TCr) {
  __shared__ __align__(16) u16 H0[2][16 * 136];
  __shared__ __align__(16) u16 H1[2][16 * 136];
  const int lane = threadIdx.x & 63, w = threadIdx.x >> 6;   // 8 waves
  const int ln = lane & 15, lq = lane >> 4;
  const int f0 = w * 16;
  const int fme = f0 + lq * 4;
  const int b0 = blockIdx.x * 16;
  const u16* wh0 = wb + O_WHH;
  const u16* wi1 = wb + O_WIH + 49152;
  const u16* wh1 = wb + O_WHH + 49152;

  // 36 loop-invariant weight frags -> AGPRs
  bf16v wH0[3][4], wI1[3][4], wH1[3][4];
#pragma unroll
  for (int g = 0; g < 3; ++g)
#pragma unroll
    for (int kt = 0; kt < 4; ++kt) {
      size_t row = (size_t)(g * 128 + f0 + ln);
      size_t col = (size_t)kt * 32 + lq * 8;
      wH0[g][kt] = ldb(wh0 + row * H_ + col);
      wI1[g][kt] = ldb(wi1 + row * H_ + col);
      wH1[g][kt] = ldb(wh1 + row * H_ + col);
    }
#pragma unroll
  for (int g = 0; g < 3; ++g)
#pragma unroll
    for (int kt = 0; kt < 4; ++kt)
      asm volatile("" : "+a"(wH0[g][kt]), "+a"(wI1[g][kt]), "+a"(wH1[g][kt]));

  float h0s[4], h1s[4];
#pragma unroll
  for (int j = 0; j < 4; ++j) {
    h0s[j] = hst[(size_t)(0 * B_ + b0 + ln) * H_ + fme + j];
    h1s[j] = hst[(size_t)(1 * B_ + b0 + ln) * H_ + fme + j];
  }
  *reinterpret_cast<u64*>(&H0[0][ln * 136 + fme]) = pk4(h0s[0], h0s[1], h0s[2], h0s[3]);
  *reinterpret_cast<u64*>(&H1[0][ln * 136 + fme]) = pk4(h1s[0], h1s[1], h1s[2], h1s[3]);
  u16* hp = h1old + (size_t)(b0 + ln) * H_ + fme;
  *reinterpret_cast<u64*>(hp) = pk4(h1s[0], h1s[1], h1s[2], h1s[3]);   // t=0 slot

  // gi0 base for this thread; advances by B*384 elements per step
  const u16* gp = gi0 + (size_t)(b0 + ln) * 384 + fme;
  u64 gq0 = *reinterpret_cast<const u64*>(gp);          // gate r
  u64 gq1 = *reinterpret_cast<const u64*>(gp + 128);    // gate z
  u64 gq2 = *reinterpret_cast<const u64*>(gp + 256);    // gate n
  gp += (size_t)B_ * 384;

  __syncthreads();

#define GRU_STEP(CUR, NXT, T)                                                   \
  {                                                                             \
    /* ---- layer 0: h-side MFMA (weights from AGPR) + precomputed gi0 ---- */  \
    f32x4 cR = {0,0,0,0}, cZ = {0,0,0,0}, cHN = {0,0,0,0};                      \
    _Pragma("unroll")                                                           \
    for (int kt = 0; kt < 4; ++kt) {                                            \
      bf16v aH = ldb(&H0[CUR][ln * 136 + kt * 32 + lq * 8]);                    \
      MFA(cR,  wH0[0][kt], aH);                                                 \
      MFA(cZ,  wH0[1][kt], aH);                                                 \
      MFA(cHN, wH0[2][kt], aH);                                                 \
    }                                                                           \
    {                                                                           \
      u32 l0 = (u32)gq0, h0w = (u32)(gq0 >> 32);                                \
      u32 l1 = (u32)gq1, h1w = (u32)(gq1 >> 32);                                \
      u32 l2 = (u32)gq2, h2w = (u32)(gq2 >> 32);                                \
      float gr[4] = {asf(l0 << 16), asf(l0 & 0xffff0000u),                      \
                     asf(h0w << 16), asf(h0w & 0xffff0000u)};                   \
      float gz[4] = {asf(l1 << 16), asf(l1 & 0xffff0000u),                      \
                     asf(h1w << 16), asf(h1w & 0xffff0000u)};                   \
      float gn[4] = {asf(l2 << 16), asf(l2 & 0xffff0000u),                      \
                     asf(h2w << 16), asf(h2w & 0xffff0000u)};                   \
      _Pragma("unroll")                                                         \
      for (int j = 0; j < 4; ++j) {                                             \
        float r = sigm(cR[j] + gr[j]);                                          \
        float z = sigm(cZ[j] + gz[j]);                                          \
        float n = tanhg(fmaf(r, cHN[j], gn[j]));                                \
        h0s[j] = fmaf(z, h0s[j] - n, n);                                        \
      }                                                                         \
      *reinterpret_cast<u64*>(&H0[NXT][ln * 136 + fme]) =                       \
          pk4(h0s[0], h0s[1], h0s[2], h0s[3]);                                  \
    }                                                                           \
    __syncthreads();                                                            \
    /* prefetch gi0 for t+1 (post-barrier; consumed next step pre-barrier) */   \
    if ((T) + 1 < TCr) {                                                        \
      gq0 = *reinterpret_cast<const u64*>(gp);                                  \
      gq1 = *reinterpret_cast<const u64*>(gp + 128);                            \
      gq2 = *reinterpret_cast<const u64*>(gp + 256);                            \
      gp += (size_t)B_ * 384;                                                   \
    }                                                                           \
    /* ---- layer 1 ---- */                                                     \
    f32x4 dR = {0,0,0,0}, dZ = {0,0,0,0}, dIN = {0,0,0,0}, dHN = {0,0,0,0};     \
    _Pragma("unroll")                                                           \
    for (int kt = 0; kt < 4; ++kt) {                                            \
      bf16v aI  = ldb(&H0[NXT][ln * 136 + kt * 32 + lq * 8]);                   \
      bf16v aH1 = ldb(&H1[CUR][ln * 136 + kt * 32 + lq * 8]);                   \
      MFA(dR,  wI1[0][kt], aI);                                                 \
      MFA(dR,  wH1[0][kt], aH1);                                                \
      MFA(dZ,  wI1[1][kt], aI);                                                 \
      MFA(dZ,  wH1[1][kt], aH1);                                                \
      MFA(dIN, wI1[2][kt], aI);                                                 \
      MFA(dHN, wH1[2][kt], aH1);                                                \
    }                                                                           \
    {                                                                           \
      _Pragma("unroll")                                                         \
      for (int j = 0; j < 4; ++j) {                                             \
        float r = sigm(dR[j]);                                                  \
        float z = sigm(dZ[j]);                                                  \
        float n = tanhg(fmaf(r, dHN[j], dIN[j]));                               \
        h1s[j] = fmaf(z, h1s[j] - n, n);                                        \
      }                                                                         \
      u64 q = pk4(h1s[0], h1s[1], h1s[2], h1s[3]);                              \
      *reinterpret_cast<u64*>(&H1[NXT][ln * 136 + fme]) = q;                    \
      if ((T) + 1 < TCr) {                                                      \
        hp += (size_t)B_ * H_;                                                  \
        *reinterpret_cast<u64*>(hp) = q;                                        \
      }                                                                         \
    }                                                                           \
  }

  for (int tt = 0; tt < TCr; tt += 2) {
    GRU_STEP(0, 1, tt)
    GRU_STEP(1, 0, tt + 1)
  }
#undef GRU_STEP

  // persist h state for next chunk
#pragma unroll
  for (int j = 0; j < 4; ++j) {
    hst[(size_t)(0 * B_ + b0 + ln) * H_ + fme + j] = h0s[j];
    hst[(size_t)(1 * B_ + b0 + ln) * H_ + fme + j] = h1s[j];
  }
}

// ============ kernel 5: post-chain + loss partials (one chunk) ============
DI void layer128(const u16* __restrict__ W, const float* __restrict__ bias,
                 const u16* A, u16* Dst, int dstOff, int nTiles, bool relu,
                 int ln, int lq) {
  bf16v a[2][4];
#pragma unroll
  for (int mt = 0; mt < 2; ++mt)
#pragma unroll
    for (int kt = 0; kt < 4; ++kt)
      a[mt][kt] = ldb(A + (mt * 16 + ln) * 136 + kt * 32 + lq * 8);
  for (int nt = 0; nt < nTiles; ++nt) {
    f32x4 c0 = {0,0,0,0}, c1 = {0,0,0,0};
#pragma unroll
    for (int kt = 0; kt < 4; ++kt) {
      bf16v b = ldb(W + (nt * 16 + ln) * 128 + kt * 32 + lq * 8);
      c0 = MFMA(a[0][kt], b, c0); c1 = MFMA(a[1][kt], b, c1);
    }
    float bv = bias[nt * 16 + ln];
#pragma unroll
    for (int mt = 0; mt < 2; ++mt)
#pragma unroll
      for (int j = 0; j < 4; ++j) {
        float v = (mt ? c1[j] : c0[j]) + bv;
        if (relu) v = fmaxf(v, 0.f);
        Dst[(mt * 16 + lq * 4 + j) * 136 + dstOff + nt * 16 + ln] = f2b(v);
      }
  }
}

__global__ __launch_bounds__(128) void k_post(
    const u16* __restrict__ phiu, const u16* __restrict__ h1old,
    const u16* __restrict__ yT, const u16* __restrict__ wb,
    const float* __restrict__ dy_b1, const float* __restrict__ dy_b2,
    const float* __restrict__ xm_b, const float* __restrict__ xlv_b,
    const float* __restrict__ px_b1, const float* __restrict__ px_b2,
    const float* __restrict__ me_b1, const float* __restrict__ me_b2,
    float* __restrict__ partials, int first) {
  __shared__ __align__(16) u16 buf[2][2][32 * 136];
  __shared__ float wsum[2];
  const int lane = threadIdx.x & 63, w = threadIdx.x >> 6;   // 2 waves
  const int ln = lane & 15, lq = lane >> 4;
  const int r0 = (blockIdx.x * 2 + w) * 32;
  u16* X = buf[w][0];
  u16* Yb = buf[w][1];

  {
    bf16v a[2][8];
#pragma unroll
    for (int mt = 0; mt < 2; ++mt)
#pragma unroll
      for (int kt = 0; kt < 8; ++kt) {
        size_t row = (size_t)(r0 + mt * 16 + ln);
        a[mt][kt] = (kt < 4) ? ldb(phiu + row * H_ + kt * 32 + lq * 8)
                             : ldb(h1old + row * H_ + (kt - 4) * 32 + lq * 8);
      }
    const u16* W = wb + O_DY_W1;
    for (int nt = 0; nt < 8; ++nt) {
      f32x4 c0 = {0,0,0,0}, c1 = {0,0,0,0};
#pragma unroll
      for (int kt = 0; kt < 8; ++kt) {
        bf16v b = ldb(W + (nt * 16 + ln) * 256 + kt * 32 + lq * 8);
        c0 = MFMA(a[0][kt], b, c0); c1 = MFMA(a[1][kt], b, c1);
      }
      float bv = dy_b1[nt * 16 + ln];
#pragma unroll
      for (int mt = 0; mt < 2; ++mt)
#pragma unroll
        for (int j = 0; j < 4; ++j) {
          float v = (mt ? c1[j] : c0[j]) + bv;
          X[(mt * 16 + lq * 4 + j) * 136 + nt * 16 + ln] = f2b(fmaxf(v, 0.f));
        }
    }
  }
  layer128(wb + O_DY_W2, dy_b2, X, Yb, 0, 8, false, ln, lq);
  layer128(wb + O_XM_W,  xm_b,  Yb, X, 0, 4, false, ln, lq);
  layer128(wb + O_XLV_W, xlv_b, Yb, X, 64, 4, false, ln, lq);
  layer128(wb + O_PX_W1, px_b1, X, Yb, 0, 8, true,  ln, lq);
  layer128(wb + O_PX_W2, px_b2, Yb, X, 0, 8, false, ln, lq);
  layer128(wb + O_ME_W1, me_b1, X, Yb, 0, 8, true,  ln, lq);

  float lsum = 0.f;
  {
    bf16v a[2][4];
#pragma unroll
    for (int mt = 0; mt < 2; ++mt)
#pragma unroll
      for (int kt = 0; kt < 4; ++kt)
        a[mt][kt] = ldb(Yb + (mt * 16 + ln) * 136 + kt * 32 + lq * 8);
    const u16* W = wb + O_ME_W2;
#pragma unroll
    for (int nt = 0; nt < 2; ++nt) {
      f32x4 c0 = {0,0,0,0}, c1 = {0,0,0,0};
#pragma unroll
      for (int kt = 0; kt < 4; ++kt) {
        bf16v b = ldb(W + (nt * 16 + ln) * 128 + kt * 32 + lq * 8);
        c0 = MFMA(a[0][kt], b, c0); c1 = MFMA(a[1][kt], b, c1);
      }
      float bv = me_b2[nt * 16 + ln];
#pragma unroll
      for (int mt = 0; mt < 2; ++mt)
#pragma unroll
        for (int j = 0; j < 4; ++j) {
          int m = mt * 16 + lq * 4 + j;
          float v = (mt ? c1[j] : c0[j]) + bv;
          float yv = b2f(yT[(size_t)(r0 + m) * 32 + nt * 16 + ln]);
          float d = v - yv;
          lsum += d * d;
        }
    }
  }
#pragma unroll
  for (int o = 32; o; o >>= 1) lsum += __shfl_down(lsum, o);
  if (lane == 0) wsum[w] = lsum;
  __syncthreads();
  if (threadIdx.x == 0) {
    float v = wsum[0] + wsum[1];
    if (first) partials[blockIdx.x] = v;
    else       partials[blockIdx.x] += v;
  }
}

// ============ kernel 6: deterministic final reduction ============
__global__ void k_finalize(const float* __restrict__ partials, float* __restrict__ out,
                           int nPart) {
  __shared__ double s[256];
  double acc = 0.0;
  for (int i = threadIdx.x; i < nPart; i += 256) acc += (double)partials[i];
  s[threadIdx.x] = acc;
  __syncthreads();
  for (int o = 128; o; o >>= 1) {
    if (threadIdx.x < o) s[threadIdx.x] += s[threadIdx.x + o];
    __syncthreads();
  }
  if (threadIdx.x == 0) out[0] = (float)s[0];
}

extern "C" void kernel_launch(void* const* d_in, const int* in_sizes, int n_in,
                              void* d_out, int out_size, void* d_ws, size_t ws_size,
                              hipStream_t stream) {
  const float* u     = (const float*)d_in[0];
  const float* y     = (const float*)d_in[1];
  const float* h0    = (const float*)d_in[2];
  const float* pu_w1 = (const float*)d_in[3];
  const float* pu_b1 = (const float*)d_in[4];
  const float* pu_w2 = (const float*)d_in[5];
  const float* pu_b2 = (const float*)d_in[6];
  const float* dy_w1 = (const float*)d_in[7];
  const float* dy_b1 = (const float*)d_in[8];
  const float* dy_w2 = (const float*)d_in[9];
  const float* dy_b2 = (const float*)d_in[10];
  const float* xm_w  = (const float*)d_in[11];
  const float* xm_b  = (const float*)d_in[12];
  const float* xlv_w = (const float*)d_in[13];
  const float* xlv_b = (const float*)d_in[14];
  const float* px_w1 = (const float*)d_in[15];
  const float* px_b1 = (const float*)d_in[16];
  const float* px_w2 = (const float*)d_in[17];
  const float* px_b2 = (const float*)d_in[18];
  const float* me_w1 = (const float*)d_in[19];
  const float* me_b1 = (const float*)d_in[20];
  const float* me_w2 = (const float*)d_in[21];
  const float* me_b2 = (const float*)d_in[22];
  const float* gih   = (const float*)d_in[23];
  const float* ghh   = (const float*)d_in[24];

  // runtime time-chunk tier vs workspace size
  int TC = 64;
  for (int cand : {256, 128}) {
    size_t ut = (size_t)cand * B_ * 32 * 2;      // uT or yT
    size_t ph = (size_t)cand * B_ * 128 * 2;     // phiu or h1old
    size_t gi = (size_t)cand * B_ * 384 * 2;     // gi0
    if (WS_DATA + 2 * ut + 2 * ph + gi <= ws_size) { TC = cand; break; }
  }
  const int NCH = T_ / TC;
  const int RC = TC * B_;
  size_t ut_b = (size_t)RC * 32 * 2, ph_b = (size_t)RC * 128 * 2;

  char* ws = (char*)d_ws;
  u16* wb    = (u16*)(ws + WS_WB);
  float* hst = (float*)(ws + WS_HST);
  float* prt = (float*)(ws + WS_PART);
  u16* uT    = (u16*)(ws + WS_DATA);
  u16* yT    = (u16*)(ws + WS_DATA + ut_b);
  u16* phiu  = (u16*)(ws + WS_DATA + 2 * ut_b);
  u16* h1o   = (u16*)(ws + WS_DATA + 2 * ut_b + ph_b);
  u16* gi0   = (u16*)(ws + WS_DATA + 2 * ut_b + 2 * ph_b);
  float* out = (float*)d_out;

  k_convert_weights<<<256, 256, 0, stream>>>(pu_w1, pu_w2, dy_w1, dy_w2, xm_w, xlv_w,
                                             px_w1, px_w2, me_w1, me_w2, gih, ghh,
                                             h0, wb, hst);
  for (int c = 0; c < NCH; ++c) {
    k_transpose<<<dim3(TC / 32, 256, 2), dim3(32, 8), 0, stream>>>(u, y, uT, yT, c * TC);
    k_phi_u<<<RC / 128, 256, 0, stream>>>(uT, wb, pu_b1, pu_b2, phiu, gi0);
    k_gru_seq<<<16, 512, 0, stream>>>(gi0, wb, hst, h1o, TC);
    k_post<<<RC / 64, 128, 0, stream>>>(phiu, h1o, yT, wb, dy_b1, dy_b2, xm_b, xlv_b,
                                        px_b1, px_b2, me_b1, me_b2, prt, c == 0 ? 1 : 0);
  }
  k_finalize<<<1, 256, 0, stream>>>(prt, out, RC / 64);
}

// Round 8
// 3063.650 us; speedup vs baseline: 1.3270x; 1.2007x over previous
//
#include <hip/hip_runtime.h>

#define DI __device__ __forceinline__

typedef unsigned short u16;
typedef unsigned int u32;
typedef unsigned long long u64;
typedef __bf16 bf16v __attribute__((ext_vector_type(8)));   // 8 bf16 = 4 VGPRs (MFMA A/B frag)
typedef float f32x4 __attribute__((ext_vector_type(4)));     // MFMA C/D frag

constexpr int B_ = 256, T_ = 2048, H_ = 128;
constexpr int BU = B_ * 32;        // 8192

// ---- bf16 weight pool offsets (elements) ----
constexpr size_t O_PU_W1 = 0;        // [128][32]
constexpr size_t O_PU_W2 = 4096;     // [128][128]
constexpr size_t O_DY_W1 = 20480;    // [128][256]
constexpr size_t O_DY_W2 = 53248;    // [128][128]
constexpr size_t O_XM_W  = 69632;    // [64][128]
constexpr size_t O_XLV_W = 77824;    // [64][128]
constexpr size_t O_PX_W1 = 86016;    // [128][128]
constexpr size_t O_PX_W2 = 102400;   // [128][128]
constexpr size_t O_ME_W1 = 118784;   // [128][128]
constexpr size_t O_ME_W2 = 135168;   // [32][128]
constexpr size_t O_WIH   = 139264;   // [2][384][128]
constexpr size_t O_WHH   = 237568;   // [2][384][128]

constexpr size_t WS_WB   = 0;
constexpr size_t WS_HST  = 0x100000;
constexpr size_t WS_PART = 0x140000;
constexpr size_t WS_DATA = 0x180000;

DI u16 f2b(float x) {
  union { float f; unsigned u; } v; v.f = x;
  unsigned r = v.u + 0x7fffu + ((v.u >> 16) & 1u);   // RNE
  return (u16)(r >> 16);
}
DI float b2f(u16 h) { union { unsigned u; float f; } v; v.u = ((unsigned)h) << 16; return v.f; }
DI float asf(u32 u) { union { unsigned u; float f; } v; v.u = u; return v.f; }
DI float sigm(float x) {
  return __builtin_amdgcn_rcpf(1.f + __builtin_amdgcn_exp2f(-1.44269504f * x));
}
DI float tanhg(float x) {
  return fmaf(2.f, __builtin_amdgcn_rcpf(1.f + __builtin_amdgcn_exp2f(-2.88539008f * x)), -1.f);
}
DI f32x4 MFMA(bf16v a, bf16v b, f32x4 c) {
  return __builtin_amdgcn_mfma_f32_16x16x32_bf16(a, b, c, 0, 0, 0);
}
// MFMA with A operand pinned in AGPRs (allocator cannot evict/sink AGPR values)
DI void MFA(f32x4& c, const bf16v& a_agpr, const bf16v& b) {
  asm("v_mfma_f32_16x16x32_bf16 %0, %1, %2, %0"
      : "+v"(c) : "a"(a_agpr), "v"(b));
}
DI bf16v ldb(const u16* p) { return *reinterpret_cast<const bf16v*>(p); }
DI u32 cvtpk(float a, float b) {
  u32 d;
  asm("v_cvt_pk_bf16_f32 %0, %1, %2" : "=v"(d) : "v"(a), "v"(b));
  return d;
}
DI u64 pk4(float a, float b, float c, float d) {
  return (u64)cvtpk(a, b) | ((u64)cvtpk(c, d) << 32);
}

// ============ kernel 1: convert weights f32 -> bf16 pool, init h state ============
__global__ void k_convert_weights(
    const float* pu_w1, const float* pu_w2, const float* dy_w1, const float* dy_w2,
    const float* xm_w, const float* xlv_w, const float* px_w1, const float* px_w2,
    const float* me_w1, const float* me_w2, const float* gih, const float* ghh,
    const float* h0, u16* wb, float* hst) {
  int i0 = blockIdx.x * blockDim.x + threadIdx.x;
  int st = gridDim.x * blockDim.x;
#define CVT(src, off, n) for (int i = i0; i < (n); i += st) wb[(off) + i] = f2b(src[i]);
  CVT(pu_w1, O_PU_W1, 4096)  CVT(pu_w2, O_PU_W2, 16384)
  CVT(dy_w1, O_DY_W1, 32768) CVT(dy_w2, O_DY_W2, 16384)
  CVT(xm_w,  O_XM_W,  8192)  CVT(xlv_w, O_XLV_W, 8192)
  CVT(px_w1, O_PX_W1, 16384) CVT(px_w2, O_PX_W2, 16384)
  CVT(me_w1, O_ME_W1, 16384) CVT(me_w2, O_ME_W2, 4096)
  CVT(gih,   O_WIH,   98304) CVT(ghh,   O_WHH,   98304)
#undef CVT
  for (int i = i0; i < 2 * B_ * H_; i += st) hst[i] = h0[i];
}

// ============ kernel 2 (prologue only): transpose u,y slice -> bf16 ============
__global__ void k_transpose(const float* __restrict__ u, const float* __restrict__ y,
                            u16* __restrict__ uT, u16* __restrict__ yT, int t0) {
  const float* src = blockIdx.z ? y : u;
  u16* dst = blockIdx.z ? yT : uT;
  __shared__ float tile[32][33];
  const int tx = threadIdx.x, ty = threadIdx.y;      // 32 x 8
  const int c0 = blockIdx.x * 32;
  const int r0 = blockIdx.y * 32;
#pragma unroll
  for (int i = 0; i < 4; ++i)
    tile[ty + i * 8][tx] = src[(size_t)(r0 + ty + i * 8) * T_ + t0 + c0 + tx];
  __syncthreads();
#pragma unroll
  for (int i = 0; i < 4; ++i)
    dst[(size_t)(c0 + ty + i * 8) * BU + r0 + tx] = f2b(tile[tx][ty + i * 8]);
}

// ===================== ROLE: GRU (byte-identical inner loop to r7) ==============
DI void role_gru(u16* smem, const u16* __restrict__ gi0, const u16* __restrict__ wb,
                 float* __restrict__ hst, u16* __restrict__ h1old, int TCr, int blk) {
  u16* SH0 = smem;          // [2][16*136]
  u16* SH1 = smem + 4352;   // [2][16*136]
  const int lane = threadIdx.x & 63, w = threadIdx.x >> 6;   // 8 waves
  const int ln = lane & 15, lq = lane >> 4;
  const int f0 = w * 16;
  const int fme = f0 + lq * 4;
  const int b0 = blk * 16;
  const u16* wh0 = wb + O_WHH;
  const u16* wi1 = wb + O_WIH + 49152;
  const u16* wh1 = wb + O_WHH + 49152;

  bf16v wH0[3][4], wI1[3][4], wH1[3][4];
#pragma unroll
  for (int g = 0; g < 3; ++g)
#pragma unroll
    for (int kt = 0; kt < 4; ++kt) {
      size_t row = (size_t)(g * 128 + f0 + ln);
      size_t col = (size_t)kt * 32 + lq * 8;
      wH0[g][kt] = ldb(wh0 + row * H_ + col);
      wI1[g][kt] = ldb(wi1 + row * H_ + col);
      wH1[g][kt] = ldb(wh1 + row * H_ + col);
    }
#pragma unroll
  for (int g = 0; g < 3; ++g)
#pragma unroll
    for (int kt = 0; kt < 4; ++kt)
      asm volatile("" : "+a"(wH0[g][kt]), "+a"(wI1[g][kt]), "+a"(wH1[g][kt]));

  float h0s[4], h1s[4];
#pragma unroll
  for (int j = 0; j < 4; ++j) {
    h0s[j] = hst[(size_t)(0 * B_ + b0 + ln) * H_ + fme + j];
    h1s[j] = hst[(size_t)(1 * B_ + b0 + ln) * H_ + fme + j];
  }
  *reinterpret_cast<u64*>(&SH0[ln * 136 + fme]) = pk4(h0s[0], h0s[1], h0s[2], h0s[3]);
  *reinterpret_cast<u64*>(&SH1[ln * 136 + fme]) = pk4(h1s[0], h1s[1], h1s[2], h1s[3]);
  u16* hp = h1old + (size_t)(b0 + ln) * H_ + fme;
  *reinterpret_cast<u64*>(hp) = pk4(h1s[0], h1s[1], h1s[2], h1s[3]);   // t=0 slot

  const u16* gp = gi0 + (size_t)(b0 + ln) * 384 + fme;
  u64 gq0 = *reinterpret_cast<const u64*>(gp);
  u64 gq1 = *reinterpret_cast<const u64*>(gp + 128);
  u64 gq2 = *reinterpret_cast<const u64*>(gp + 256);
  gp += (size_t)B_ * 384;

  __syncthreads();

#define GRU_STEP(CUR, NXT, T)                                                   \
  {                                                                             \
    u16* H0c = SH0 + (CUR) * 2176; u16* H0n = SH0 + (NXT) * 2176;               \
    u16* H1c = SH1 + (CUR) * 2176; u16* H1n = SH1 + (NXT) * 2176;               \
    f32x4 cR = {0,0,0,0}, cZ = {0,0,0,0}, cHN = {0,0,0,0};                      \
    _Pragma("unroll")                                                           \
    for (int kt = 0; kt < 4; ++kt) {                                            \
      bf16v aH = ldb(&H0c[ln * 136 + kt * 32 + lq * 8]);                        \
      MFA(cR,  wH0[0][kt], aH);                                                 \
      MFA(cZ,  wH0[1][kt], aH);                                                 \
      MFA(cHN, wH0[2][kt], aH);                                                 \
    }                                                                           \
    {                                                                           \
      u32 l0 = (u32)gq0, h0w = (u32)(gq0 >> 32);                                \
      u32 l1 = (u32)gq1, h1w = (u32)(gq1 >> 32);                                \
      u32 l2 = (u32)gq2, h2w = (u32)(gq2 >> 32);                                \
      float gr[4] = {asf(l0 << 16), asf(l0 & 0xffff0000u),                      \
                     asf(h0w << 16), asf(h0w & 0xffff0000u)};                   \
      float gz[4] = {asf(l1 << 16), asf(l1 & 0xffff0000u),                      \
                     asf(h1w << 16), asf(h1w & 0xffff0000u)};                   \
      float gn[4] = {asf(l2 << 16), asf(l2 & 0xffff0000u),                      \
                     asf(h2w << 16), asf(h2w & 0xffff0000u)};                   \
      _Pragma("unroll")                                                         \
      for (int j = 0; j < 4; ++j) {                                             \
        float r = sigm(cR[j] + gr[j]);                                          \
        float z = sigm(cZ[j] + gz[j]);                                          \
        float n = tanhg(fmaf(r, cHN[j], gn[j]));                                \
        h0s[j] = fmaf(z, h0s[j] - n, n);                                        \
      }                                                                         \
      *reinterpret_cast<u64*>(&H0n[ln * 136 + fme]) =                           \
          pk4(h0s[0], h0s[1], h0s[2], h0s[3]);                                  \
    }                                                                           \
    __syncthreads();                                                            \
    if ((T) + 1 < TCr) {                                                        \
      gq0 = *reinterpret_cast<const u64*>(gp);                                  \
      gq1 = *reinterpret_cast<const u64*>(gp + 128);                            \
      gq2 = *reinterpret_cast<const u64*>(gp + 256);                            \
      gp += (size_t)B_ * 384;                                                   \
    }                                                                           \
    f32x4 dR = {0,0,0,0}, dZ = {0,0,0,0}, dIN = {0,0,0,0}, dHN = {0,0,0,0};     \
    _Pragma("unroll")                                                           \
    for (int kt = 0; kt < 4; ++kt) {                                            \
      bf16v aI  = ldb(&H0n[ln * 136 + kt * 32 + lq * 8]);                       \
      bf16v aH1 = ldb(&H1c[ln * 136 + kt * 32 + lq * 8]);                       \
      MFA(dR,  wI1[0][kt], aI);                                                 \
      MFA(dR,  wH1[0][kt], aH1);                                                \
      MFA(dZ,  wI1[1][kt], aI);                                                 \
      MFA(dZ,  wH1[1][kt], aH1);                                                \
      MFA(dIN, wI1[2][kt], aI);                                                 \
      MFA(dHN, wH1[2][kt], aH1);                                                \
    }                                                                           \
    {                                                                           \
      _Pragma("unroll")                                                         \
      for (int j = 0; j < 4; ++j) {                                             \
        float r = sigm(dR[j]);                                                  \
        float z = sigm(dZ[j]);                                                  \
        float n = tanhg(fmaf(r, dHN[j], dIN[j]));                               \
        h1s[j] = fmaf(z, h1s[j] - n, n);                                        \
      }                                                                         \
      u64 q = pk4(h1s[0], h1s[1], h1s[2], h1s[3]);                              \
      *reinterpret_cast<u64*>(&H1n[ln * 136 + fme]) = q;                        \
      if ((T) + 1 < TCr) {                                                      \
        hp += (size_t)B_ * H_;                                                  \
        *reinterpret_cast<u64*>(hp) = q;                                        \
      }                                                                         \
    }                                                                           \
  }

  for (int tt = 0; tt < TCr; tt += 2) {
    GRU_STEP(0, 1, tt)
    GRU_STEP(1, 0, tt + 1)
  }
#undef GRU_STEP

#pragma unroll
  for (int j = 0; j < 4; ++j) {
    hst[(size_t)(0 * B_ + b0 + ln) * H_ + fme + j] = h0s[j];
    hst[(size_t)(1 * B_ + b0 + ln) * H_ + fme + j] = h1s[j];
  }
}

// ===================== ROLE: post-chain (8 waves x 32 rows) =====================
DI void layer128(const u16* __restrict__ W, const float* __restrict__ bias,
                 const u16* A, u16* Dst, int dstOff, int nTiles, bool relu,
                 int ln, int lq) {
  bf16v a[2][4];
#pragma unroll
  for (int mt = 0; mt < 2; ++mt)
#pragma unroll
    for (int kt = 0; kt < 4; ++kt)
      a[mt][kt] = ldb(A + (mt * 16 + ln) * 136 + kt * 32 + lq * 8);
  for (int nt = 0; nt < nTiles; ++nt) {
    f32x4 c0 = {0,0,0,0}, c1 = {0,0,0,0};
#pragma unroll
    for (int kt = 0; kt < 4; ++kt) {
      bf16v b = ldb(W + (nt * 16 + ln) * 128 + kt * 32 + lq * 8);
      c0 = MFMA(a[0][kt], b, c0); c1 = MFMA(a[1][kt], b, c1);
    }
    float bv = bias[nt * 16 + ln];
#pragma unroll
    for (int mt = 0; mt < 2; ++mt)
#pragma unroll
      for (int j = 0; j < 4; ++j) {
        float v = (mt ? c1[j] : c0[j]) + bv;
        if (relu) v = fmaxf(v, 0.f);
        Dst[(mt * 16 + lq * 4 + j) * 136 + dstOff + nt * 16 + ln] = f2b(v);
      }
  }
}

DI void role_post(u16* smem, const u16* __restrict__ phiu, const u16* __restrict__ h1old,
                  const u16* __restrict__ yT, const u16* __restrict__ wb,
                  const float* dy_b1, const float* dy_b2, const float* xm_b,
                  const float* xlv_b, const float* px_b1, const float* px_b2,
                  const float* me_b1, const float* me_b2,
                  float* __restrict__ partials, int first, int blk) {
  const int lane = threadIdx.x & 63, w = threadIdx.x >> 6;   // 8 waves
  const int ln = lane & 15, lq = lane >> 4;
  const int r0 = (blk * 8 + w) * 32;
  u16* X = smem + w * 8704;
  u16* Yb = X + 4352;
  float* wsum = (float*)(smem + 69632);

  {
    bf16v a[2][8];
#pragma unroll
    for (int mt = 0; mt < 2; ++mt)
#pragma unroll
      for (int kt = 0; kt < 8; ++kt) {
        size_t row = (size_t)(r0 + mt * 16 + ln);
        a[mt][kt] = (kt < 4) ? ldb(phiu + row * H_ + kt * 32 + lq * 8)
                             : ldb(h1old + row * H_ + (kt - 4) * 32 + lq * 8);
      }
    const u16* W = wb + O_DY_W1;
    for (int nt = 0; nt < 8; ++nt) {
      f32x4 c0 = {0,0,0,0}, c1 = {0,0,0,0};
#pragma unroll
      for (int kt = 0; kt < 8; ++kt) {
        bf16v b = ldb(W + (nt * 16 + ln) * 256 + kt * 32 + lq * 8);
        c0 = MFMA(a[0][kt], b, c0); c1 = MFMA(a[1][kt], b, c1);
      }
      float bv = dy_b1[nt * 16 + ln];
#pragma unroll
      for (int mt = 0; mt < 2; ++mt)
#pragma unroll
        for (int j = 0; j < 4; ++j) {
          float v = (mt ? c1[j] : c0[j]) + bv;
          X[(mt * 16 + lq * 4 + j) * 136 + nt * 16 + ln] = f2b(fmaxf(v, 0.f));
        }
    }
  }
  layer128(wb + O_DY_W2, dy_b2, X, Yb, 0, 8, false, ln, lq);
  layer128(wb + O_XM_W,  xm_b,  Yb, X, 0, 4, false, ln, lq);
  layer128(wb + O_XLV_W, xlv_b, Yb, X, 64, 4, false, ln, lq);
  layer128(wb + O_PX_W1, px_b1, X, Yb, 0, 8, true,  ln, lq);
  layer128(wb + O_PX_W2, px_b2, Yb, X, 0, 8, false, ln, lq);
  layer128(wb + O_ME_W1, me_b1, X, Yb, 0, 8, true,  ln, lq);

  float lsum = 0.f;
  {
    bf16v a[2][4];
#pragma unroll
    for (int mt = 0; mt < 2; ++mt)
#pragma unroll
      for (int kt = 0; kt < 4; ++kt)
        a[mt][kt] = ldb(Yb + (mt * 16 + ln) * 136 + kt * 32 + lq * 8);
    const u16* W = wb + O_ME_W2;
#pragma unroll
    for (int nt = 0; nt < 2; ++nt) {
      f32x4 c0 = {0,0,0,0}, c1 = {0,0,0,0};
#pragma unroll
      for (int kt = 0; kt < 4; ++kt) {
        bf16v b = ldb(W + (nt * 16 + ln) * 128 + kt * 32 + lq * 8);
        c0 = MFMA(a[0][kt], b, c0); c1 = MFMA(a[1][kt], b, c1);
      }
      float bv = me_b2[nt * 16 + ln];
#pragma unroll
      for (int mt = 0; mt < 2; ++mt)
#pragma unroll
        for (int j = 0; j < 4; ++j) {
          int m = mt * 16 + lq * 4 + j;
          float v = (mt ? c1[j] : c0[j]) + bv;
          float yv = b2f(yT[(size_t)(r0 + m) * 32 + nt * 16 + ln]);
          float d = v - yv;
          lsum += d * d;
        }
    }
  }
#pragma unroll
  for (int o = 32; o; o >>= 1) lsum += __shfl_down(lsum, o);
  if (lane == 0) wsum[w] = lsum;
  __syncthreads();
  if (threadIdx.x == 0) {
    float v = 0.f;
#pragma unroll
    for (int i = 0; i < 8; ++i) v += wsum[i];
    if (first) partials[blk] = v;
    else       partials[blk] += v;
  }
}

// ===================== ROLE: phi_u + gi0 (8 waves x 32 rows) ====================
DI void role_phiu(u16* smem, const u16* __restrict__ uT, const u16* __restrict__ wb,
                  const float* __restrict__ pu_b1, const float* __restrict__ pu_b2,
                  u16* __restrict__ phiu, u16* __restrict__ gi0, int blk) {
  const int lane = threadIdx.x & 63, w = threadIdx.x >> 6;   // 8 waves
  const int ln = lane & 15, lq = lane >> 4;
  const int r0 = (blk * 8 + w) * 32;
  u16* hb  = smem + w * 4352;
  u16* hb2 = smem + 34816 + w * 4352;

  bf16v a0 = ldb(uT + (size_t)(r0 + ln) * 32 + lq * 8);
  bf16v a1 = ldb(uT + (size_t)(r0 + 16 + ln) * 32 + lq * 8);
  const u16* w1 = wb + O_PU_W1;
#pragma unroll
  for (int nt = 0; nt < 8; ++nt) {
    f32x4 c0 = {0.f, 0.f, 0.f, 0.f}, c1 = {0.f, 0.f, 0.f, 0.f};
    bf16v b = ldb(w1 + (nt * 16 + ln) * 32 + lq * 8);
    c0 = MFMA(a0, b, c0); c1 = MFMA(a1, b, c1);
    float bv = pu_b1[nt * 16 + ln];
#pragma unroll
    for (int j = 0; j < 4; ++j) {
      hb[(lq * 4 + j) * 136 + nt * 16 + ln]      = f2b(fmaxf(c0[j] + bv, 0.f));
      hb[(16 + lq * 4 + j) * 136 + nt * 16 + ln] = f2b(fmaxf(c1[j] + bv, 0.f));
    }
  }
  bf16v a[2][4];
#pragma unroll
  for (int mt = 0; mt < 2; ++mt)
#pragma unroll
    for (int kt = 0; kt < 4; ++kt)
      a[mt][kt] = ldb(hb + (mt * 16 + ln) * 136 + kt * 32 + lq * 8);
  const u16* w2 = wb + O_PU_W2;
#pragma unroll
  for (int nt = 0; nt < 8; ++nt) {
    f32x4 c0 = {0.f, 0.f, 0.f, 0.f}, c1 = {0.f, 0.f, 0.f, 0.f};
#pragma unroll
    for (int kt = 0; kt < 4; ++kt) {
      bf16v b = ldb(w2 + (nt * 16 + ln) * 128 + kt * 32 + lq * 8);
      c0 = MFMA(a[0][kt], b, c0); c1 = MFMA(a[1][kt], b, c1);
    }
    float bv = pu_b2[nt * 16 + ln];
#pragma unroll
    for (int mt = 0; mt < 2; ++mt)
#pragma unroll
      for (int j = 0; j < 4; ++j) {
        float v = (mt ? c1[j] : c0[j]) + bv;
        hb2[(mt * 16 + lq * 4 + j) * 136 + nt * 16 + ln] = f2b(v);
      }
  }
  __syncthreads();

#pragma unroll
  for (int i = 0; i < 16; ++i) {
    int idx = lane + 64 * i;
    int row = idx >> 5, c4 = idx & 31;
    u64 v = *reinterpret_cast<const u64*>(&hb2[row * 136 + c4 * 4]);
    *reinterpret_cast<u64*>(&phiu[(size_t)(r0 + row) * 128 + c4 * 4]) = v;
  }

  bf16v bP[2][4];
#pragma unroll
  for (int bh = 0; bh < 2; ++bh)
#pragma unroll
    for (int kt = 0; kt < 4; ++kt)
      bP[bh][kt] = ldb(&hb2[(bh * 16 + ln) * 136 + kt * 32 + lq * 8]);
  const u16* wih0 = wb + O_WIH;
  for (int nt = 0; nt < 24; ++nt) {
    bf16v aW[4];
#pragma unroll
    for (int kt = 0; kt < 4; ++kt)
      aW[kt] = ldb(wih0 + (size_t)(nt * 16 + ln) * 128 + kt * 32 + lq * 8);
#pragma unroll
    for (int bh = 0; bh < 2; ++bh) {
      f32x4 c = {0.f, 0.f, 0.f, 0.f};
#pragma unroll
      for (int kt = 0; kt < 4; ++kt) c = MFMA(aW[kt], bP[bh][kt], c);
      u64 q = pk4(c[0], c[1], c[2], c[3]);
      *reinterpret_cast<u64*>(
          &gi0[(size_t)(r0 + bh * 16 + ln) * 384 + nt * 16 + lq * 4]) = q;
    }
  }
}

// ===================== ROLE: transpose (2 workers x 4 tiles) ====================
DI void role_transpose(u16* smem, const float* __restrict__ u, const float* __restrict__ y,
                       u16* __restrict__ uT, u16* __restrict__ yT, int t0, int blk, int TCr) {
  float* tile = (float*)smem;                 // [2][32*33]
  const int worker = threadIdx.x >> 8;        // 0..1
  const int tid = threadIdx.x & 255;
  const int tx = tid & 31, ty = tid >> 5;     // 32 x 8
  float* tl = tile + worker * (32 * 33);
  const int ntt = TCr / 32;
  for (int i = 0; i < 4; ++i) {
    int gtile = blk * 8 + worker * 4 + i;
    int tt = gtile % ntt;
    int rest = gtile / ntt;
    int rr = rest & 255, uy = rest >> 8;
    const float* src = uy ? y : u;
    u16* dst = uy ? yT : uT;
    int c0 = tt * 32, r0 = rr * 32;
#pragma unroll
    for (int k = 0; k < 4; ++k)
      tl[(ty + k * 8) * 33 + tx] = src[(size_t)(r0 + ty + k * 8) * T_ + t0 + c0 + tx];
    __syncthreads();
#pragma unroll
    for (int k = 0; k < 4; ++k)
      dst[(size_t)(c0 + ty + k * 8) * BU + r0 + tx] = f2b(tl[tx * 33 + ty + k * 8]);
    __syncthreads();
  }
}

// ===================== MEGA kernel: role dispatch by blockIdx ===================
__global__ __launch_bounds__(512, 2) void k_mega(
    const float* u, const float* yy,
    const u16* uT_r, u16* uT_w, u16* yT_w, const u16* yT_r,
    const u16* phiu_r, u16* phiu_w,
    const u16* gi0_r, u16* gi0_w,
    const u16* h1_r, u16* h1_w,
    const u16* wb, float* hst,
    const float* pu_b1, const float* pu_b2,
    const float* dy_b1, const float* dy_b2, const float* xm_b, const float* xlv_b,
    const float* px_b1, const float* px_b2, const float* me_b1, const float* me_b2,
    float* partials, int first,
    int TCr, int nG, int nP, int nU, int t0T) {
  __shared__ __align__(16) u16 smem[69664];   // 139,328 B: max over roles
  int b = blockIdx.x;
  if (b < nG) { role_gru(smem, gi0_r, wb, hst, h1_w, TCr, b); return; }
  b -= nG;
  if (b < nP) {
    role_post(smem, phiu_r, h1_r, yT_r, wb, dy_b1, dy_b2, xm_b, xlv_b,
              px_b1, px_b2, me_b1, me_b2, partials, first, b);
    return;
  }
  b -= nP;
  if (b < nU) { role_phiu(smem, uT_r, wb, pu_b1, pu_b2, phiu_w, gi0_w, b); return; }
  b -= nU;
  role_transpose(smem, u, yy, uT_w, yT_w, t0T, b, TCr);
}

// ============ finalize ============
__global__ void k_finalize(const float* __restrict__ partials, float* __restrict__ out,
                           int nPart) {
  __shared__ double s[256];
  double acc = 0.0;
  for (int i = threadIdx.x; i < nPart; i += 256) acc += (double)partials[i];
  s[threadIdx.x] = acc;
  __syncthreads();
  for (int o = 128; o; o >>= 1) {
    if (threadIdx.x < o) s[threadIdx.x] += s[threadIdx.x + o];
    __syncthreads();
  }
  if (threadIdx.x == 0) out[0] = (float)s[0];
}

extern "C" void kernel_launch(void* const* d_in, const int* in_sizes, int n_in,
                              void* d_out, int out_size, void* d_ws, size_t ws_size,
                              hipStream_t stream) {
  const float* u     = (const float*)d_in[0];
  const float* y     = (const float*)d_in[1];
  const float* h0    = (const float*)d_in[2];
  const float* pu_w1 = (const float*)d_in[3];
  const float* pu_b1 = (const float*)d_in[4];
  const float* pu_w2 = (const float*)d_in[5];
  const float* pu_b2 = (const float*)d_in[6];
  const float* dy_w1 = (const float*)d_in[7];
  const float* dy_b1 = (const float*)d_in[8];
  const float* dy_w2 = (const float*)d_in[9];
  const float* dy_b2 = (const float*)d_in[10];
  const float* xm_w  = (const float*)d_in[11];
  const float* xm_b  = (const float*)d_in[12];
  const float* xlv_w = (const float*)d_in[13];
  const float* xlv_b = (const float*)d_in[14];
  const float* px_w1 = (const float*)d_in[15];
  const float* px_b1 = (const float*)d_in[16];
  const float* px_w2 = (const float*)d_in[17];
  const float* px_b2 = (const float*)d_in[18];
  const float* me_w1 = (const float*)d_in[19];
  const float* me_b1 = (const float*)d_in[20];
  const float* me_w2 = (const float*)d_in[21];
  const float* me_b2 = (const float*)d_in[22];
  const float* gih   = (const float*)d_in[23];
  const float* ghh   = (const float*)d_in[24];

  // time-chunk tier vs workspace (ring buffers: uT x2, yT x4, phiu x3, h1 x2, gi0 x2)
  int TC = 64;
  for (int cand : {256, 128}) {
    size_t ut = (size_t)cand * B_ * 32 * 2;
    size_t ph = (size_t)cand * B_ * 128 * 2;
    size_t gi = (size_t)cand * B_ * 384 * 2;
    if (WS_DATA + 6 * ut + 5 * ph + 2 * gi <= ws_size) { TC = cand; break; }
  }
  const int NCH = T_ / TC;
  const int RC = TC * B_;
  size_t ut_b = (size_t)RC * 32 * 2, ph_b = (size_t)RC * 128 * 2, gi_b = (size_t)RC * 384 * 2;

  char* ws = (char*)d_ws;
  u16* wb    = (u16*)(ws + WS_WB);
  float* hst = (float*)(ws + WS_HST);
  float* prt = (float*)(ws + WS_PART);
  char* p = ws + WS_DATA;
  u16* uTb[2]; u16* yTb[4]; u16* phb[3]; u16* h1b[2]; u16* gib[2];
  for (int i = 0; i < 2; ++i) { uTb[i] = (u16*)p; p += ut_b; }
  for (int i = 0; i < 4; ++i) { yTb[i] = (u16*)p; p += ut_b; }
  for (int i = 0; i < 3; ++i) { phb[i] = (u16*)p; p += ph_b; }
  for (int i = 0; i < 2; ++i) { h1b[i] = (u16*)p; p += ph_b; }
  for (int i = 0; i < 2; ++i) { gib[i] = (u16*)p; p += gi_b; }
  float* out = (float*)d_out;

  const int nPostB = RC / 256;            // post blocks per chunk
  const int nPhiB  = RC / 256;            // phi_u blocks per chunk
  const int nTrB   = (TC / 32) * 64;      // transpose blocks per chunk (tiles/8)

  k_convert_weights<<<256, 256, 0, stream>>>(pu_w1, pu_w2, dy_w1, dy_w2, xm_w, xlv_w,
                                             px_w1, px_w2, me_w1, me_w2, gih, ghh,
                                             h0, wb, hst);
  // prologue: transpose chunks 0,1 ; phi_u chunk 0
  k_transpose<<<dim3(TC / 32, 256, 2), dim3(32, 8), 0, stream>>>(u, y, uTb[0], yTb[0], 0);
  if (NCH > 1)
    k_transpose<<<dim3(TC / 32, 256, 2), dim3(32, 8), 0, stream>>>(u, y, uTb[1], yTb[1], TC);
  k_mega<<<nPhiB, 512, 0, stream>>>(u, y, uTb[0], uTb[0], yTb[0], yTb[0],
                                    phb[0], phb[0], gib[0], gib[0], h1b[0], h1b[0],
                                    wb, hst, pu_b1, pu_b2, dy_b1, dy_b2, xm_b, xlv_b,
                                    px_b1, px_b2, me_b1, me_b2, prt, 0,
                                    TC, 0, 0, nPhiB, 0);
  // main pipeline: mega(c) = GRU(c) || post(c-1) || phi_u(c+1) || transpose(c+2)
  for (int c = 0; c <= NCH; ++c) {
    int nG = (c < NCH) ? 16 : 0;
    int nP = (c >= 1) ? nPostB : 0;
    int nU = (c + 1 < NCH) ? nPhiB : 0;
    int nT = (c + 2 < NCH) ? nTrB : 0;
    int grid = nG + nP + nU + nT;
    if (!grid) continue;
    k_mega<<<grid, 512, 0, stream>>>(
        u, y,
        uTb[(c + 1) & 1], uTb[(c + 2) & 1], yTb[(c + 2) & 3],
        yTb[c >= 1 ? (c - 1) & 3 : 0],
        phb[c >= 1 ? (c - 1) % 3 : 0], phb[(c + 1) % 3],
        gib[c & 1], gib[(c + 1) & 1],
        h1b[c >= 1 ? (c - 1) & 1 : 0], h1b[c & 1],
        wb, hst, pu_b1, pu_b2, dy_b1, dy_b2, xm_b, xlv_b,
        px_b1, px_b2, me_b1, me_b2,
        prt, (c == 1) ? 1 : 0,
        TC, nG, nP, nU, (c + 2) * TC);
  }
  k_finalize<<<1, 256, 0, stream>>>(prt, out, nPostB);
}

// Round 9
// 3062.592 us; speedup vs baseline: 1.3274x; 1.0003x over previous
//
#include <hip/hip_runtime.h>

#define DI __device__ __forceinline__

typedef unsigned short u16;
typedef unsigned int u32;
typedef unsigned long long u64;
typedef __bf16 bf16v __attribute__((ext_vector_type(8)));   // 8 bf16 = 4 VGPRs (MFMA A/B frag)
typedef float f32x4 __attribute__((ext_vector_type(4)));     // MFMA C/D frag

constexpr int B_ = 256, T_ = 2048, H_ = 128;
constexpr int BU = B_ * 32;        // 8192

// ---- bf16 weight pool offsets (elements) ----
constexpr size_t O_PU_W1 = 0;        // [128][32]
constexpr size_t O_PU_W2 = 4096;     // [128][128]
constexpr size_t O_DY_W1 = 20480;    // [128][256]
constexpr size_t O_DY_W2 = 53248;    // [128][128]
constexpr size_t O_XM_W  = 69632;    // [64][128]
constexpr size_t O_XLV_W = 77824;    // [64][128]
constexpr size_t O_PX_W1 = 86016;    // [128][128]
constexpr size_t O_PX_W2 = 102400;   // [128][128]
constexpr size_t O_ME_W1 = 118784;   // [128][128]
constexpr size_t O_ME_W2 = 135168;   // [32][128]
constexpr size_t O_WIH   = 139264;   // [2][384][128]
constexpr size_t O_WHH   = 237568;   // [2][384][128]

constexpr size_t WS_WB   = 0;
constexpr size_t WS_HST  = 0x100000;
constexpr size_t WS_PART = 0x140000;
constexpr size_t WS_DATA = 0x180000;

DI u16 f2b(float x) {
  union { float f; unsigned u; } v; v.f = x;
  unsigned r = v.u + 0x7fffu + ((v.u >> 16) & 1u);   // RNE
  return (u16)(r >> 16);
}
DI float b2f(u16 h) { union { unsigned u; float f; } v; v.u = ((unsigned)h) << 16; return v.f; }
DI float asf(u32 u) { union { unsigned u; float f; } v; v.u = u; return v.f; }
DI float sigm(float x) {
  return __builtin_amdgcn_rcpf(1.f + __builtin_amdgcn_exp2f(-1.44269504f * x));
}
DI float tanhg(float x) {
  return fmaf(2.f, __builtin_amdgcn_rcpf(1.f + __builtin_amdgcn_exp2f(-2.88539008f * x)), -1.f);
}
DI f32x4 MFMA(bf16v a, bf16v b, f32x4 c) {
  return __builtin_amdgcn_mfma_f32_16x16x32_bf16(a, b, c, 0, 0, 0);
}
// MFMA with A operand pinned in AGPRs (allocator cannot evict/sink AGPR values)
DI void MFA(f32x4& c, const bf16v& a_agpr, const bf16v& b) {
  asm("v_mfma_f32_16x16x32_bf16 %0, %1, %2, %0"
      : "+v"(c) : "a"(a_agpr), "v"(b));
}
DI bf16v ldb(const u16* p) { return *reinterpret_cast<const bf16v*>(p); }
DI u32 cvtpk(float a, float b) {
  u32 d;
  asm("v_cvt_pk_bf16_f32 %0, %1, %2" : "=v"(d) : "v"(a), "v"(b));
  return d;
}
DI u64 pk4(float a, float b, float c, float d) {
  return (u64)cvtpk(a, b) | ((u64)cvtpk(c, d) << 32);
}
// LDS-only barrier: waits LDS ops (lgkmcnt) but does NOT drain vmcnt —
// global h1old stores / gi0 prefetch loads stay in flight across steps.
// "memory" clobber pins compile-time ordering of the ds_read/ds_write around it.
DI void bar_lds() {
  asm volatile("s_waitcnt lgkmcnt(0)\n\ts_barrier" ::: "memory");
}

// ============ kernel 1: convert weights f32 -> bf16 pool, init h state ============
__global__ void k_convert_weights(
    const float* pu_w1, const float* pu_w2, const float* dy_w1, const float* dy_w2,
    const float* xm_w, const float* xlv_w, const float* px_w1, const float* px_w2,
    const float* me_w1, const float* me_w2, const float* gih, const float* ghh,
    const float* h0, u16* wb, float* hst) {
  int i0 = blockIdx.x * blockDim.x + threadIdx.x;
  int st = gridDim.x * blockDim.x;
#define CVT(src, off, n) for (int i = i0; i < (n); i += st) wb[(off) + i] = f2b(src[i]);
  CVT(pu_w1, O_PU_W1, 4096)  CVT(pu_w2, O_PU_W2, 16384)
  CVT(dy_w1, O_DY_W1, 32768) CVT(dy_w2, O_DY_W2, 16384)
  CVT(xm_w,  O_XM_W,  8192)  CVT(xlv_w, O_XLV_W, 8192)
  CVT(px_w1, O_PX_W1, 16384) CVT(px_w2, O_PX_W2, 16384)
  CVT(me_w1, O_ME_W1, 16384) CVT(me_w2, O_ME_W2, 4096)
  CVT(gih,   O_WIH,   98304) CVT(ghh,   O_WHH,   98304)
#undef CVT
  for (int i = i0; i < 2 * B_ * H_; i += st) hst[i] = h0[i];
}

// ============ kernel 2 (prologue only): transpose u,y slice -> bf16 ============
__global__ void k_transpose(const float* __restrict__ u, const float* __restrict__ y,
                            u16* __restrict__ uT, u16* __restrict__ yT, int t0) {
  const float* src = blockIdx.z ? y : u;
  u16* dst = blockIdx.z ? yT : uT;
  __shared__ float tile[32][33];
  const int tx = threadIdx.x, ty = threadIdx.y;      // 32 x 8
  const int c0 = blockIdx.x * 32;
  const int r0 = blockIdx.y * 32;
#pragma unroll
  for (int i = 0; i < 4; ++i)
    tile[ty + i * 8][tx] = src[(size_t)(r0 + ty + i * 8) * T_ + t0 + c0 + tx];
  __syncthreads();
#pragma unroll
  for (int i = 0; i < 4; ++i)
    dst[(size_t)(c0 + ty + i * 8) * BU + r0 + tx] = f2b(tile[tx][ty + i * 8]);
}

// ===================== ROLE: GRU =====================
DI void role_gru(u16* smem, const u16* __restrict__ gi0, const u16* __restrict__ wb,
                 float* __restrict__ hst, u16* __restrict__ h1old, int TCr, int blk) {
  u16* SH0 = smem;          // [2][16*136]
  u16* SH1 = smem + 4352;   // [2][16*136]
  const int lane = threadIdx.x & 63, w = threadIdx.x >> 6;   // 8 waves
  const int ln = lane & 15, lq = lane >> 4;
  const int f0 = w * 16;
  const int fme = f0 + lq * 4;
  const int b0 = blk * 16;
  const u16* wh0 = wb + O_WHH;
  const u16* wi1 = wb + O_WIH + 49152;
  const u16* wh1 = wb + O_WHH + 49152;

  bf16v wH0[3][4], wI1[3][4], wH1[3][4];
#pragma unroll
  for (int g = 0; g < 3; ++g)
#pragma unroll
    for (int kt = 0; kt < 4; ++kt) {
      size_t row = (size_t)(g * 128 + f0 + ln);
      size_t col = (size_t)kt * 32 + lq * 8;
      wH0[g][kt] = ldb(wh0 + row * H_ + col);
      wI1[g][kt] = ldb(wi1 + row * H_ + col);
      wH1[g][kt] = ldb(wh1 + row * H_ + col);
    }
#pragma unroll
  for (int g = 0; g < 3; ++g)
#pragma unroll
    for (int kt = 0; kt < 4; ++kt)
      asm volatile("" : "+a"(wH0[g][kt]), "+a"(wI1[g][kt]), "+a"(wH1[g][kt]));

  float h0s[4], h1s[4];
#pragma unroll
  for (int j = 0; j < 4; ++j) {
    h0s[j] = hst[(size_t)(0 * B_ + b0 + ln) * H_ + fme + j];
    h1s[j] = hst[(size_t)(1 * B_ + b0 + ln) * H_ + fme + j];
  }
  *reinterpret_cast<u64*>(&SH0[ln * 136 + fme]) = pk4(h0s[0], h0s[1], h0s[2], h0s[3]);
  *reinterpret_cast<u64*>(&SH1[ln * 136 + fme]) = pk4(h1s[0], h1s[1], h1s[2], h1s[3]);
  u16* hp = h1old + (size_t)(b0 + ln) * H_ + fme;
  *reinterpret_cast<u64*>(hp) = pk4(h1s[0], h1s[1], h1s[2], h1s[3]);   // t=0 slot

  const u16* gp = gi0 + (size_t)(b0 + ln) * 384 + fme;
  u64 gq0 = *reinterpret_cast<const u64*>(gp);
  u64 gq1 = *reinterpret_cast<const u64*>(gp + 128);
  u64 gq2 = *reinterpret_cast<const u64*>(gp + 256);
  gp += (size_t)B_ * 384;

  __syncthreads();

#define GRU_STEP(CUR, NXT, T)                                                   \
  {                                                                             \
    u16* H0c = SH0 + (CUR) * 2176; u16* H0n = SH0 + (NXT) * 2176;               \
    u16* H1c = SH1 + (CUR) * 2176; u16* H1n = SH1 + (NXT) * 2176;               \
    f32x4 cR = {0,0,0,0}, cZ = {0,0,0,0}, cHN = {0,0,0,0};                      \
    _Pragma("unroll")                                                           \
    for (int kt = 0; kt < 4; ++kt) {                                            \
      bf16v aH = ldb(&H0c[ln * 136 + kt * 32 + lq * 8]);                        \
      MFA(cR,  wH0[0][kt], aH);                                                 \
      MFA(cZ,  wH0[1][kt], aH);                                                 \
      MFA(cHN, wH0[2][kt], aH);                                                 \
    }                                                                           \
    {                                                                           \
      u32 l0 = (u32)gq0, h0w = (u32)(gq0 >> 32);                                \
      u32 l1 = (u32)gq1, h1w = (u32)(gq1 >> 32);                                \
      u32 l2 = (u32)gq2, h2w = (u32)(gq2 >> 32);                                \
      float gr[4] = {asf(l0 << 16), asf(l0 & 0xffff0000u),                      \
                     asf(h0w << 16), asf(h0w & 0xffff0000u)};                   \
      float gz[4] = {asf(l1 << 16), asf(l1 & 0xffff0000u),                      \
                     asf(h1w << 16), asf(h1w & 0xffff0000u)};                   \
      float gn[4] = {asf(l2 << 16), asf(l2 & 0xffff0000u),                      \
                     asf(h2w << 16), asf(h2w & 0xffff0000u)};                   \
      _Pragma("unroll")                                                         \
      for (int j = 0; j < 4; ++j) {                                             \
        float r = sigm(cR[j] + gr[j]);                                          \
        float z = sigm(cZ[j] + gz[j]);                                          \
        float n = tanhg(fmaf(r, cHN[j], gn[j]));                                \
        h0s[j] = fmaf(z, h0s[j] - n, n);                                        \
      }                                                                         \
      *reinterpret_cast<u64*>(&H0n[ln * 136 + fme]) =                           \
          pk4(h0s[0], h0s[1], h0s[2], h0s[3]);                                  \
    }                                                                           \
    bar_lds();   /* LDS-only barrier: no vmcnt(0) drain */                      \
    if ((T) + 1 < TCr) {                                                        \
      gq0 = *reinterpret_cast<const u64*>(gp);                                  \
      gq1 = *reinterpret_cast<const u64*>(gp + 128);                            \
      gq2 = *reinterpret_cast<const u64*>(gp + 256);                            \
      gp += (size_t)B_ * 384;                                                   \
    }                                                                           \
    f32x4 dR = {0,0,0,0}, dZ = {0,0,0,0}, dIN = {0,0,0,0}, dHN = {0,0,0,0};     \
    _Pragma("unroll")                                                           \
    for (int kt = 0; kt < 4; ++kt) {                                            \
      bf16v aI  = ldb(&H0n[ln * 136 + kt * 32 + lq * 8]);                       \
      bf16v aH1 = ldb(&H1c[ln * 136 + kt * 32 + lq * 8]);                       \
      MFA(dR,  wI1[0][kt], aI);                                                 \
      MFA(dR,  wH1[0][kt], aH1);                                                \
      MFA(dZ,  wI1[1][kt], aI);                                                 \
      MFA(dZ,  wH1[1][kt], aH1);                                                \
      MFA(dIN, wI1[2][kt], aI);                                                 \
      MFA(dHN, wH1[2][kt], aH1);                                                \
    }                                                                           \
    {                                                                           \
      _Pragma("unroll")                                                         \
      for (int j = 0; j < 4; ++j) {                                             \
        float r = sigm(dR[j]);                                                  \
        float z = sigm(dZ[j]);                                                  \
        float n = tanhg(fmaf(r, dHN[j], dIN[j]));                               \
        h1s[j] = fmaf(z, h1s[j] - n, n);                                        \
      }                                                                         \
      u64 q = pk4(h1s[0], h1s[1], h1s[2], h1s[3]);                              \
      *reinterpret_cast<u64*>(&H1n[ln * 136 + fme]) = q;                        \
      if ((T) + 1 < TCr) {                                                      \
        hp += (size_t)B_ * H_;                                                  \
        *reinterpret_cast<u64*>(hp) = q;                                        \
      }                                                                         \
    }                                                                           \
  }

  for (int tt = 0; tt < TCr; tt += 2) {
    GRU_STEP(0, 1, tt)
    GRU_STEP(1, 0, tt + 1)
  }
#undef GRU_STEP

#pragma unroll
  for (int j = 0; j < 4; ++j) {
    hst[(size_t)(0 * B_ + b0 + ln) * H_ + fme + j] = h0s[j];
    hst[(size_t)(1 * B_ + b0 + ln) * H_ + fme + j] = h1s[j];
  }
}

// ===================== ROLE: post-chain (8 waves x 32 rows) =====================
DI void layer128(const u16* __restrict__ W, const float* __restrict__ bias,
                 const u16* A, u16* Dst, int dstOff, int nTiles, bool relu,
                 int ln, int lq) {
  bf16v a[2][4];
#pragma unroll
  for (int mt = 0; mt < 2; ++mt)
#pragma unroll
    for (int kt = 0; kt < 4; ++kt)
      a[mt][kt] = ldb(A + (mt * 16 + ln) * 136 + kt * 32 + lq * 8);
  for (int nt = 0; nt < nTiles; ++nt) {
    f32x4 c0 = {0,0,0,0}, c1 = {0,0,0,0};
#pragma unroll
    for (int kt = 0; kt < 4; ++kt) {
      bf16v b = ldb(W + (nt * 16 + ln) * 128 + kt * 32 + lq * 8);
      c0 = MFMA(a[0][kt], b, c0); c1 = MFMA(a[1][kt], b, c1);
    }
    float bv = bias[nt * 16 + ln];
#pragma unroll
    for (int mt = 0; mt < 2; ++mt)
#pragma unroll
      for (int j = 0; j < 4; ++j) {
        float v = (mt ? c1[j] : c0[j]) + bv;
        if (relu) v = fmaxf(v, 0.f);
        Dst[(mt * 16 + lq * 4 + j) * 136 + dstOff + nt * 16 + ln] = f2b(v);
      }
  }
}

DI void role_post(u16* smem, const u16* __restrict__ phiu, const u16* __restrict__ h1old,
                  const u16* __restrict__ yT, const u16* __restrict__ wb,
                  const float* dy_b1, const float* dy_b2, const float* xm_b,
                  const float* xlv_b, const float* px_b1, const float* px_b2,
                  const float* me_b1, const float* me_b2,
                  float* __restrict__ partials, int first, int blk) {
  const int lane = threadIdx.x & 63, w = threadIdx.x >> 6;   // 8 waves
  const int ln = lane & 15, lq = lane >> 4;
  const int r0 = (blk * 8 + w) * 32;
  u16* X = smem + w * 8704;
  u16* Yb = X + 4352;
  float* wsum = (float*)(smem + 69632);

  {
    bf16v a[2][8];
#pragma unroll
    for (int mt = 0; mt < 2; ++mt)
#pragma unroll
      for (int kt = 0; kt < 8; ++kt) {
        size_t row = (size_t)(r0 + mt * 16 + ln);
        a[mt][kt] = (kt < 4) ? ldb(phiu + row * H_ + kt * 32 + lq * 8)
                             : ldb(h1old + row * H_ + (kt - 4) * 32 + lq * 8);
      }
    const u16* W = wb + O_DY_W1;
    for (int nt = 0; nt < 8; ++nt) {
      f32x4 c0 = {0,0,0,0}, c1 = {0,0,0,0};
#pragma unroll
      for (int kt = 0; kt < 8; ++kt) {
        bf16v b = ldb(W + (nt * 16 + ln) * 256 + kt * 32 + lq * 8);
        c0 = MFMA(a[0][kt], b, c0); c1 = MFMA(a[1][kt], b, c1);
      }
      float bv = dy_b1[nt * 16 + ln];
#pragma unroll
      for (int mt = 0; mt < 2; ++mt)
#pragma unroll
        for (int j = 0; j < 4; ++j) {
          float v = (mt ? c1[j] : c0[j]) + bv;
          X[(mt * 16 + lq * 4 + j) * 136 + nt * 16 + ln] = f2b(fmaxf(v, 0.f));
        }
    }
  }
  layer128(wb + O_DY_W2, dy_b2, X, Yb, 0, 8, false, ln, lq);
  layer128(wb + O_XM_W,  xm_b,  Yb, X, 0, 4, false, ln, lq);
  layer128(wb + O_XLV_W, xlv_b, Yb, X, 64, 4, false, ln, lq);
  layer128(wb + O_PX_W1, px_b1, X, Yb, 0, 8, true,  ln, lq);
  layer128(wb + O_PX_W2, px_b2, Yb, X, 0, 8, false, ln, lq);
  layer128(wb + O_ME_W1, me_b1, X, Yb, 0, 8, true,  ln, lq);

  float lsum = 0.f;
  {
    bf16v a[2][4];
#pragma unroll
    for (int mt = 0; mt < 2; ++mt)
#pragma unroll
      for (int kt = 0; kt < 4; ++kt)
        a[mt][kt] = ldb(Yb + (mt * 16 + ln) * 136 + kt * 32 + lq * 8);
    const u16* W = wb + O_ME_W2;
#pragma unroll
    for (int nt = 0; nt < 2; ++nt) {
      f32x4 c0 = {0,0,0,0}, c1 = {0,0,0,0};
#pragma unroll
      for (int kt = 0; kt < 4; ++kt) {
        bf16v b = ldb(W + (nt * 16 + ln) * 128 + kt * 32 + lq * 8);
        c0 = MFMA(a[0][kt], b, c0); c1 = MFMA(a[1][kt], b, c1);
      }
      float bv = me_b2[nt * 16 + ln];
#pragma unroll
      for (int mt = 0; mt < 2; ++mt)
#pragma unroll
        for (int j = 0; j < 4; ++j) {
          int m = mt * 16 + lq * 4 + j;
          float v = (mt ? c1[j] : c0[j]) + bv;
          float yv = b2f(yT[(size_t)(r0 + m) * 32 + nt * 16 + ln]);
          float d = v - yv;
          lsum += d * d;
        }
    }
  }
#pragma unroll
  for (int o = 32; o; o >>= 1) lsum += __shfl_down(lsum, o);
  if (lane == 0) wsum[w] = lsum;
  __syncthreads();
  if (threadIdx.x == 0) {
    float v = 0.f;
#pragma unroll
    for (int i = 0; i < 8; ++i) v += wsum[i];
    if (first) partials[blk] = v;
    else       partials[blk] += v;
  }
}

// ===================== ROLE: phi_u + gi0 (8 waves x 32 rows) ====================
DI void role_phiu(u16* smem, const u16* __restrict__ uT, const u16* __restrict__ wb,
                  const float* __restrict__ pu_b1, const float* __restrict__ pu_b2,
                  u16* __restrict__ phiu, u16* __restrict__ gi0, int blk) {
  const int lane = threadIdx.x & 63, w = threadIdx.x >> 6;   // 8 waves
  const int ln = lane & 15, lq = lane >> 4;
  const int r0 = (blk * 8 + w) * 32;
  u16* hb  = smem + w * 4352;
  u16* hb2 = smem + 34816 + w * 4352;

  bf16v a0 = ldb(uT + (size_t)(r0 + ln) * 32 + lq * 8);
  bf16v a1 = ldb(uT + (size_t)(r0 + 16 + ln) * 32 + lq * 8);
  const u16* w1 = wb + O_PU_W1;
#pragma unroll
  for (int nt = 0; nt < 8; ++nt) {
    f32x4 c0 = {0.f, 0.f, 0.f, 0.f}, c1 = {0.f, 0.f, 0.f, 0.f};
    bf16v b = ldb(w1 + (nt * 16 + ln) * 32 + lq * 8);
    c0 = MFMA(a0, b, c0); c1 = MFMA(a1, b, c1);
    float bv = pu_b1[nt * 16 + ln];
#pragma unroll
    for (int j = 0; j < 4; ++j) {
      hb[(lq * 4 + j) * 136 + nt * 16 + ln]      = f2b(fmaxf(c0[j] + bv, 0.f));
      hb[(16 + lq * 4 + j) * 136 + nt * 16 + ln] = f2b(fmaxf(c1[j] + bv, 0.f));
    }
  }
  bf16v a[2][4];
#pragma unroll
  for (int mt = 0; mt < 2; ++mt)
#pragma unroll
    for (int kt = 0; kt < 4; ++kt)
      a[mt][kt] = ldb(hb + (mt * 16 + ln) * 136 + kt * 32 + lq * 8);
  const u16* w2 = wb + O_PU_W2;
#pragma unroll
  for (int nt = 0; nt < 8; ++nt) {
    f32x4 c0 = {0.f, 0.f, 0.f, 0.f}, c1 = {0.f, 0.f, 0.f, 0.f};
#pragma unroll
    for (int kt = 0; kt < 4; ++kt) {
      bf16v b = ldb(w2 + (nt * 16 + ln) * 128 + kt * 32 + lq * 8);
      c0 = MFMA(a[0][kt], b, c0); c1 = MFMA(a[1][kt], b, c1);
    }
    float bv = pu_b2[nt * 16 + ln];
#pragma unroll
    for (int mt = 0; mt < 2; ++mt)
#pragma unroll
      for (int j = 0; j < 4; ++j) {
        float v = (mt ? c1[j] : c0[j]) + bv;
        hb2[(mt * 16 + lq * 4 + j) * 136 + nt * 16 + ln] = f2b(v);
      }
  }
  __syncthreads();

#pragma unroll
  for (int i = 0; i < 16; ++i) {
    int idx = lane + 64 * i;
    int row = idx >> 5, c4 = idx & 31;
    u64 v = *reinterpret_cast<const u64*>(&hb2[row * 136 + c4 * 4]);
    *reinterpret_cast<u64*>(&phiu[(size_t)(r0 + row) * 128 + c4 * 4]) = v;
  }

  bf16v bP[2][4];
#pragma unroll
  for (int bh = 0; bh < 2; ++bh)
#pragma unroll
    for (int kt = 0; kt < 4; ++kt)
      bP[bh][kt] = ldb(&hb2[(bh * 16 + ln) * 136 + kt * 32 + lq * 8]);
  const u16* wih0 = wb + O_WIH;
  for (int nt = 0; nt < 24; ++nt) {
    bf16v aW[4];
#pragma unroll
    for (int kt = 0; kt < 4; ++kt)
      aW[kt] = ldb(wih0 + (size_t)(nt * 16 + ln) * 128 + kt * 32 + lq * 8);
#pragma unroll
    for (int bh = 0; bh < 2; ++bh) {
      f32x4 c = {0.f, 0.f, 0.f, 0.f};
#pragma unroll
      for (int kt = 0; kt < 4; ++kt) c = MFMA(aW[kt], bP[bh][kt], c);
      u64 q = pk4(c[0], c[1], c[2], c[3]);
      *reinterpret_cast<u64*>(
          &gi0[(size_t)(r0 + bh * 16 + ln) * 384 + nt * 16 + lq * 4]) = q;
    }
  }
}

// ===================== ROLE: transpose (2 workers x 4 tiles) ====================
DI void role_transpose(u16* smem, const float* __restrict__ u, const float* __restrict__ y,
                       u16* __restrict__ uT, u16* __restrict__ yT, int t0, int blk, int TCr) {
  float* tile = (float*)smem;                 // [2][32*33]
  const int worker = threadIdx.x >> 8;        // 0..1
  const int tid = threadIdx.x & 255;
  const int tx = tid & 31, ty = tid >> 5;     // 32 x 8
  float* tl = tile + worker * (32 * 33);
  const int ntt = TCr / 32;
  for (int i = 0; i < 4; ++i) {
    int gtile = blk * 8 + worker * 4 + i;
    int tt = gtile % ntt;
    int rest = gtile / ntt;
    int rr = rest & 255, uy = rest >> 8;
    const float* src = uy ? y : u;
    u16* dst = uy ? yT : uT;
    int c0 = tt * 32, r0 = rr * 32;
#pragma unroll
    for (int k = 0; k < 4; ++k)
      tl[(ty + k * 8) * 33 + tx] = src[(size_t)(r0 + ty + k * 8) * T_ + t0 + c0 + tx];
    __syncthreads();
#pragma unroll
    for (int k = 0; k < 4; ++k)
      dst[(size_t)(c0 + ty + k * 8) * BU + r0 + tx] = f2b(tl[tx * 33 + ty + k * 8]);
    __syncthreads();
  }
}

// ===================== MEGA kernel: role dispatch by blockIdx ===================
__global__ __launch_bounds__(512, 2) void k_mega(
    const float* u, const float* yy,
    const u16* uT_r, u16* uT_w, u16* yT_w, const u16* yT_r,
    const u16* phiu_r, u16* phiu_w,
    const u16* gi0_r, u16* gi0_w,
    const u16* h1_r, u16* h1_w,
    const u16* wb, float* hst,
    const float* pu_b1, const float* pu_b2,
    const float* dy_b1, const float* dy_b2, const float* xm_b, const float* xlv_b,
    const float* px_b1, const float* px_b2, const float* me_b1, const float* me_b2,
    float* partials, int first,
    int TCr, int nG, int nP, int nU, int t0T) {
  __shared__ __align__(16) u16 smem[69664];   // 139,328 B: max over roles
  int b = blockIdx.x;
  if (b < nG) { role_gru(smem, gi0_r, wb, hst, h1_w, TCr, b); return; }
  b -= nG;
  if (b < nP) {
    role_post(smem, phiu_r, h1_r, yT_r, wb, dy_b1, dy_b2, xm_b, xlv_b,
              px_b1, px_b2, me_b1, me_b2, partials, first, b);
    return;
  }
  b -= nP;
  if (b < nU) { role_phiu(smem, uT_r, wb, pu_b1, pu_b2, phiu_w, gi0_w, b); return; }
  b -= nU;
  role_transpose(smem, u, yy, uT_w, yT_w, t0T, b, TCr);
}

// ============ finalize ============
__global__ void k_finalize(const float* __restrict__ partials, float* __restrict__ out,
                           int nPart) {
  __shared__ double s[256];
  double acc = 0.0;
  for (int i = threadIdx.x; i < nPart; i += 256) acc += (double)partials[i];
  s[threadIdx.x] = acc;
  __syncthreads();
  for (int o = 128; o; o >>= 1) {
    if (threadIdx.x < o) s[threadIdx.x] += s[threadIdx.x + o];
    __syncthreads();
  }
  if (threadIdx.x == 0) out[0] = (float)s[0];
}

extern "C" void kernel_launch(void* const* d_in, const int* in_sizes, int n_in,
                              void* d_out, int out_size, void* d_ws, size_t ws_size,
                              hipStream_t stream) {
  const float* u     = (const float*)d_in[0];
  const float* y     = (const float*)d_in[1];
  const float* h0    = (const float*)d_in[2];
  const float* pu_w1 = (const float*)d_in[3];
  const float* pu_b1 = (const float*)d_in[4];
  const float* pu_w2 = (const float*)d_in[5];
  const float* pu_b2 = (const float*)d_in[6];
  const float* dy_w1 = (const float*)d_in[7];
  const float* dy_b1 = (const float*)d_in[8];
  const float* dy_w2 = (const float*)d_in[9];
  const float* dy_b2 = (const float*)d_in[10];
  const float* xm_w  = (const float*)d_in[11];
  const float* xm_b  = (const float*)d_in[12];
  const float* xlv_w = (const float*)d_in[13];
  const float* xlv_b = (const float*)d_in[14];
  const float* px_w1 = (const float*)d_in[15];
  const float* px_b1 = (const float*)d_in[16];
  const float* px_w2 = (const float*)d_in[17];
  const float* px_b2 = (const float*)d_in[18];
  const float* me_w1 = (const float*)d_in[19];
  const float* me_b1 = (const float*)d_in[20];
  const float* me_w2 = (const float*)d_in[21];
  const float* me_b2 = (const float*)d_in[22];
  const float* gih   = (const float*)d_in[23];
  const float* ghh   = (const float*)d_in[24];

  // time-chunk tier vs workspace (ring buffers: uT x2, yT x4, phiu x3, h1 x2, gi0 x2)
  int TC = 64;
  for (int cand : {256, 128}) {
    size_t ut = (size_t)cand * B_ * 32 * 2;
    size_t ph = (size_t)cand * B_ * 128 * 2;
    size_t gi = (size_t)cand * B_ * 384 * 2;
    if (WS_DATA + 6 * ut + 5 * ph + 2 * gi <= ws_size) { TC = cand; break; }
  }
  const int NCH = T_ / TC;
  const int RC = TC * B_;
  size_t ut_b = (size_t)RC * 32 * 2, ph_b = (size_t)RC * 128 * 2, gi_b = (size_t)RC * 384 * 2;

  char* ws = (char*)d_ws;
  u16* wb    = (u16*)(ws + WS_WB);
  float* hst = (float*)(ws + WS_HST);
  float* prt = (float*)(ws + WS_PART);
  char* p = ws + WS_DATA;
  u16* uTb[2]; u16* yTb[4]; u16* phb[3]; u16* h1b[2]; u16* gib[2];
  for (int i = 0; i < 2; ++i) { uTb[i] = (u16*)p; p += ut_b; }
  for (int i = 0; i < 4; ++i) { yTb[i] = (u16*)p; p += ut_b; }
  for (int i = 0; i < 3; ++i) { phb[i] = (u16*)p; p += ph_b; }
  for (int i = 0; i < 2; ++i) { h1b[i] = (u16*)p; p += ph_b; }
  for (int i = 0; i < 2; ++i) { gib[i] = (u16*)p; p += gi_b; }
  float* out = (float*)d_out;

  const int nPostB = RC / 256;            // post blocks per chunk
  const int nPhiB  = RC / 256;            // phi_u blocks per chunk
  const int nTrB   = (TC / 32) * 64;      // transpose blocks per chunk (tiles/8)

  k_convert_weights<<<256, 256, 0, stream>>>(pu_w1, pu_w2, dy_w1, dy_w2, xm_w, xlv_w,
                                             px_w1, px_w2, me_w1, me_w2, gih, ghh,
                                             h0, wb, hst);
  // prologue: transpose chunks 0,1 ; phi_u chunk 0
  k_transpose<<<dim3(TC / 32, 256, 2), dim3(32, 8), 0, stream>>>(u, y, uTb[0], yTb[0], 0);
  if (NCH > 1)
    k_transpose<<<dim3(TC / 32, 256, 2), dim3(32, 8), 0, stream>>>(u, y, uTb[1], yTb[1], TC);
  k_mega<<<nPhiB, 512, 0, stream>>>(u, y, uTb[0], uTb[0], yTb[0], yTb[0],
                                    phb[0], phb[0], gib[0], gib[0], h1b[0], h1b[0],
                                    wb, hst, pu_b1, pu_b2, dy_b1, dy_b2, xm_b, xlv_b,
                                    px_b1, px_b2, me_b1, me_b2, prt, 0,
                                    TC, 0, 0, nPhiB, 0);
  // main pipeline: mega(c) = GRU(c) || post(c-1) || phi_u(c+1) || transpose(c+2)
  for (int c = 0; c <= NCH; ++c) {
    int nG = (c < NCH) ? 16 : 0;
    int nP = (c >= 1) ? nPostB : 0;
    int nU = (c + 1 < NCH) ? nPhiB : 0;
    int nT = (c + 2 < NCH) ? nTrB : 0;
    int grid = nG + nP + nU + nT;
    if (!grid) continue;
    k_mega<<<grid, 512, 0, stream>>>(
        u, y,
        uTb[(c + 1) & 1], uTb[(c + 2) & 1], yTb[(c + 2) & 3],
        yTb[c >= 1 ? (c - 1) & 3 : 0],
        phb[c >= 1 ? (c - 1) % 3 : 0], phb[(c + 1) % 3],
        gib[c & 1], gib[(c + 1) & 1],
        h1b[c >= 1 ? (c - 1) & 1 : 0], h1b[c & 1],
        wb, hst, pu_b1, pu_b2, dy_b1, dy_b2, xm_b, xlv_b,
        px_b1, px_b2, me_b1, me_b2,
        prt, (c == 1) ? 1 : 0,
        TC, nG, nP, nU, (c + 2) * TC);
  }
  k_finalize<<<1, 256, 0, stream>>>(prt, out, nPostB);
}

// Round 10
// 2750.814 us; speedup vs baseline: 1.4779x; 1.1133x over previous
//
#include <hip/hip_runtime.h>

#define DI __device__ __forceinline__

typedef unsigned short u16;
typedef unsigned int u32;
typedef unsigned long long u64;
typedef __bf16 bf16v __attribute__((ext_vector_type(8)));   // 8 bf16 = 4 VGPRs (MFMA A/B frag)
typedef float f32x4 __attribute__((ext_vector_type(4)));     // MFMA C/D frag

constexpr int B_ = 256, T_ = 2048, H_ = 128;
constexpr int BU = B_ * 32;        // 8192

// ---- bf16 weight pool offsets (elements) ----
constexpr size_t O_PU_W1 = 0;        // [128][32]
constexpr size_t O_PU_W2 = 4096;     // [128][128]
constexpr size_t O_DY_W1 = 20480;    // [128][256]
constexpr size_t O_DY_W2 = 53248;    // [128][128]
constexpr size_t O_XM_W  = 69632;    // [64][128]
constexpr size_t O_XLV_W = 77824;    // [64][128]
constexpr size_t O_PX_W1 = 86016;    // [128][128]
constexpr size_t O_PX_W2 = 102400;   // [128][128]
constexpr size_t O_ME_W1 = 118784;   // [128][128]
constexpr size_t O_ME_W2 = 135168;   // [32][128]
constexpr size_t O_WIH   = 139264;   // [2][384][128]
constexpr size_t O_WHH   = 237568;   // [2][384][128]

constexpr size_t WS_WB   = 0;
constexpr size_t WS_HST  = 0x100000;
constexpr size_t WS_PART = 0x140000;
constexpr size_t WS_DATA = 0x180000;

DI u16 f2b(float x) {
  union { float f; unsigned u; } v; v.f = x;
  unsigned r = v.u + 0x7fffu + ((v.u >> 16) & 1u);   // RNE
  return (u16)(r >> 16);
}
DI float b2f(u16 h) { union { unsigned u; float f; } v; v.u = ((unsigned)h) << 16; return v.f; }
DI float asf(u32 u) { union { unsigned u; float f; } v; v.u = u; return v.f; }
DI float sigm(float x) {
  return __builtin_amdgcn_rcpf(1.f + __builtin_amdgcn_exp2f(-1.44269504f * x));
}
DI float tanhg(float x) {
  return fmaf(2.f, __builtin_amdgcn_rcpf(1.f + __builtin_amdgcn_exp2f(-2.88539008f * x)), -1.f);
}
DI f32x4 MFMA(bf16v a, bf16v b, f32x4 c) {
  return __builtin_amdgcn_mfma_f32_16x16x32_bf16(a, b, c, 0, 0, 0);
}
// MFMA with A operand pinned in AGPRs (allocator cannot evict/sink AGPR values)
DI void MFA(f32x4& c, const bf16v& a_agpr, const bf16v& b) {
  asm("v_mfma_f32_16x16x32_bf16 %0, %1, %2, %0"
      : "+v"(c) : "a"(a_agpr), "v"(b));
}
DI bf16v ldb(const u16* p) { return *reinterpret_cast<const bf16v*>(p); }
DI u32 cvtpk(float a, float b) {
  u32 d;
  asm("v_cvt_pk_bf16_f32 %0, %1, %2" : "=v"(d) : "v"(a), "v"(b));
  return d;
}
DI u64 pk4(float a, float b, float c, float d) {
  return (u64)cvtpk(a, b) | ((u64)cvtpk(c, d) << 32);
}
// LDS-only barrier: waits LDS ops (lgkmcnt) but does NOT drain vmcnt.
DI void bar_lds() {
  asm volatile("s_waitcnt lgkmcnt(0)\n\ts_barrier" ::: "memory");
}

// ============ kernel 1: convert weights f32 -> bf16 pool, init h state ============
__global__ void k_convert_weights(
    const float* pu_w1, const float* pu_w2, const float* dy_w1, const float* dy_w2,
    const float* xm_w, const float* xlv_w, const float* px_w1, const float* px_w2,
    const float* me_w1, const float* me_w2, const float* gih, const float* ghh,
    const float* h0, u16* wb, float* hst) {
  int i0 = blockIdx.x * blockDim.x + threadIdx.x;
  int st = gridDim.x * blockDim.x;
#define CVT(src, off, n) for (int i = i0; i < (n); i += st) wb[(off) + i] = f2b(src[i]);
  CVT(pu_w1, O_PU_W1, 4096)  CVT(pu_w2, O_PU_W2, 16384)
  CVT(dy_w1, O_DY_W1, 32768) CVT(dy_w2, O_DY_W2, 16384)
  CVT(xm_w,  O_XM_W,  8192)  CVT(xlv_w, O_XLV_W, 8192)
  CVT(px_w1, O_PX_W1, 16384) CVT(px_w2, O_PX_W2, 16384)
  CVT(me_w1, O_ME_W1, 16384) CVT(me_w2, O_ME_W2, 4096)
  CVT(gih,   O_WIH,   98304) CVT(ghh,   O_WHH,   98304)
#undef CVT
  for (int i = i0; i < 2 * B_ * H_; i += st) hst[i] = h0[i];
}

// ============ kernel 2 (prologue only): transpose u,y slice -> bf16 ============
__global__ void k_transpose(const float* __restrict__ u, const float* __restrict__ y,
                            u16* __restrict__ uT, u16* __restrict__ yT, int t0) {
  const float* src = blockIdx.z ? y : u;
  u16* dst = blockIdx.z ? yT : uT;
  __shared__ float tile[32][33];
  const int tx = threadIdx.x, ty = threadIdx.y;      // 32 x 8
  const int c0 = blockIdx.x * 32;
  const int r0 = blockIdx.y * 32;
#pragma unroll
  for (int i = 0; i < 4; ++i)
    tile[ty + i * 8][tx] = src[(size_t)(r0 + ty + i * 8) * T_ + t0 + c0 + tx];
  __syncthreads();
#pragma unroll
  for (int i = 0; i < 4; ++i)
    dst[(size_t)(c0 + ty + i * 8) * BU + r0 + tx] = f2b(tile[tx][ty + i * 8]);
}

// ===================== ROLE: GRU — layer-skewed pipeline =====================
// Period s computes L0(t=s) AND L1(t=s-1) in ONE barrier phase:
//  - L1's input aI = h0(s-1) is the SAME LDS data as L0's aH -> shared read
//  - barriers 2/step -> 1/step; LDS reads 12 -> 8 b128/wave/step
// Arithmetic per element is bit-identical to the unskewed version.
DI void role_gru(u16* smem, const u16* __restrict__ gi0, const u16* __restrict__ wb,
                 float* __restrict__ hst, u16* __restrict__ h1old, int TCr, int blk) {
  u16* SH0 = smem;          // [2][16*136]  h0 ping-pong: parity p holds h0(t) with t&1==p
  u16* SH1 = smem + 4352;   // [2][16*136]  h1 ping-pong
  const int lane = threadIdx.x & 63, w = threadIdx.x >> 6;   // 8 waves
  const int ln = lane & 15, lq = lane >> 4;
  const int f0 = w * 16;
  const int fme = f0 + lq * 4;
  const int b0 = blk * 16;
  const u16* wh0 = wb + O_WHH;
  const u16* wi1 = wb + O_WIH + 49152;
  const u16* wh1 = wb + O_WHH + 49152;

  bf16v wH0[3][4], wI1[3][4], wH1[3][4];
#pragma unroll
  for (int g = 0; g < 3; ++g)
#pragma unroll
    for (int kt = 0; kt < 4; ++kt) {
      size_t row = (size_t)(g * 128 + f0 + ln);
      size_t col = (size_t)kt * 32 + lq * 8;
      wH0[g][kt] = ldb(wh0 + row * H_ + col);
      wI1[g][kt] = ldb(wi1 + row * H_ + col);
      wH1[g][kt] = ldb(wh1 + row * H_ + col);
    }
#pragma unroll
  for (int g = 0; g < 3; ++g)
#pragma unroll
    for (int kt = 0; kt < 4; ++kt)
      asm volatile("" : "+a"(wH0[g][kt]), "+a"(wI1[g][kt]), "+a"(wH1[g][kt]));

  float h0s[4], h1s[4];
#pragma unroll
  for (int j = 0; j < 4; ++j) {
    h0s[j] = hst[(size_t)(0 * B_ + b0 + ln) * H_ + fme + j];
    h1s[j] = hst[(size_t)(1 * B_ + b0 + ln) * H_ + fme + j];
  }
  // initial state = "h(-1)" -> parity-1 buffers
  *reinterpret_cast<u64*>(&SH0[2176 + ln * 136 + fme]) = pk4(h0s[0], h0s[1], h0s[2], h0s[3]);
  *reinterpret_cast<u64*>(&SH1[2176 + ln * 136 + fme]) = pk4(h1s[0], h1s[1], h1s[2], h1s[3]);
  u16* hp = h1old + (size_t)(b0 + ln) * H_ + fme;
  *reinterpret_cast<u64*>(hp) = pk4(h1s[0], h1s[1], h1s[2], h1s[3]);   // slot 0

  const u16* gp = gi0 + (size_t)(b0 + ln) * 384 + fme;
  u64 gq0 = *reinterpret_cast<const u64*>(gp);          // gi0(t=0)
  u64 gq1 = *reinterpret_cast<const u64*>(gp + 128);
  u64 gq2 = *reinterpret_cast<const u64*>(gp + 256);
  gp += (size_t)B_ * 384;

  __syncthreads();

  // ---- period 0: L0(t=0) only ----
  {
    f32x4 cR = {0,0,0,0}, cZ = {0,0,0,0}, cHN = {0,0,0,0};
#pragma unroll
    for (int kt = 0; kt < 4; ++kt) {
      bf16v aH = ldb(&SH0[2176 + ln * 136 + kt * 32 + lq * 8]);   // h0(-1), parity 1
      MFA(cR,  wH0[0][kt], aH);
      MFA(cZ,  wH0[1][kt], aH);
      MFA(cHN, wH0[2][kt], aH);
    }
    u32 l0 = (u32)gq0, h0w = (u32)(gq0 >> 32);
    u32 l1 = (u32)gq1, h1w = (u32)(gq1 >> 32);
    u32 l2 = (u32)gq2, h2w = (u32)(gq2 >> 32);
    float gr[4] = {asf(l0 << 16), asf(l0 & 0xffff0000u), asf(h0w << 16), asf(h0w & 0xffff0000u)};
    float gz[4] = {asf(l1 << 16), asf(l1 & 0xffff0000u), asf(h1w << 16), asf(h1w & 0xffff0000u)};
    float gn[4] = {asf(l2 << 16), asf(l2 & 0xffff0000u), asf(h2w << 16), asf(h2w & 0xffff0000u)};
#pragma unroll
    for (int j = 0; j < 4; ++j) {
      float r = sigm(cR[j] + gr[j]);
      float z = sigm(cZ[j] + gz[j]);
      float n = tanhg(fmaf(r, cHN[j], gn[j]));
      h0s[j] = fmaf(z, h0s[j] - n, n);
    }
    *reinterpret_cast<u64*>(&SH0[0 * 2176 + ln * 136 + fme]) =
        pk4(h0s[0], h0s[1], h0s[2], h0s[3]);                       // h0(0), parity 0
    // prefetch gi0(t=1)
    gq0 = *reinterpret_cast<const u64*>(gp);
    gq1 = *reinterpret_cast<const u64*>(gp + 128);
    gq2 = *reinterpret_cast<const u64*>(gp + 256);
    gp += (size_t)B_ * 384;
    bar_lds();
  }

  // Period s (1..TCr): read h0(s-1) [parity (s-1)&1] and h1(s-2) [parity s&1];
  // L1(t=s-1) always; L0(t=s) iff s<TCr; write h0(s)->parity s&1, h1(s-1)->parity (s-1)&1.
#define GRU_PERIOD(H0R, H0W, DOL0, SLOT_OK, PF)                                 \
  {                                                                             \
    bf16v aH[4], aG[4];                                                         \
    _Pragma("unroll")                                                           \
    for (int kt = 0; kt < 4; ++kt) {                                            \
      aH[kt] = ldb(&SH0[(H0R) * 2176 + ln * 136 + kt * 32 + lq * 8]);           \
      aG[kt] = ldb(&SH1[(H0W) * 2176 + ln * 136 + kt * 32 + lq * 8]);           \
    }                                                                           \
    f32x4 dR = {0,0,0,0}, dZ = {0,0,0,0}, dIN = {0,0,0,0}, dHN = {0,0,0,0};     \
    _Pragma("unroll")                                                           \
    for (int kt = 0; kt < 4; ++kt) {                                            \
      MFA(dR,  wI1[0][kt], aH[kt]);  MFA(dR,  wH1[0][kt], aG[kt]);              \
      MFA(dZ,  wI1[1][kt], aH[kt]);  MFA(dZ,  wH1[1][kt], aG[kt]);              \
      MFA(dIN, wI1[2][kt], aH[kt]);  MFA(dHN, wH1[2][kt], aG[kt]);              \
    }                                                                           \
    if (DOL0) {                                                                 \
      f32x4 cR = {0,0,0,0}, cZ = {0,0,0,0}, cHN = {0,0,0,0};                    \
      _Pragma("unroll")                                                         \
      for (int kt = 0; kt < 4; ++kt) {                                          \
        MFA(cR,  wH0[0][kt], aH[kt]);                                           \
        MFA(cZ,  wH0[1][kt], aH[kt]);                                           \
        MFA(cHN, wH0[2][kt], aH[kt]);                                           \
      }                                                                         \
      u32 l0 = (u32)gq0, h0w = (u32)(gq0 >> 32);                                \
      u32 l1 = (u32)gq1, h1w = (u32)(gq1 >> 32);                                \
      u32 l2 = (u32)gq2, h2w = (u32)(gq2 >> 32);                                \
      float gr[4] = {asf(l0 << 16), asf(l0 & 0xffff0000u),                      \
                     asf(h0w << 16), asf(h0w & 0xffff0000u)};                   \
      float gz[4] = {asf(l1 << 16), asf(l1 & 0xffff0000u),                      \
                     asf(h1w << 16), asf(h1w & 0xffff0000u)};                   \
      float gn[4] = {asf(l2 << 16), asf(l2 & 0xffff0000u),                      \
                     asf(h2w << 16), asf(h2w & 0xffff0000u)};                   \
      _Pragma("unroll")                                                         \
      for (int j = 0; j < 4; ++j) {                                             \
        float r = sigm(cR[j] + gr[j]);                                          \
        float z = sigm(cZ[j] + gz[j]);                                          \
        float n = tanhg(fmaf(r, cHN[j], gn[j]));                                \
        h0s[j] = fmaf(z, h0s[j] - n, n);                                        \
      }                                                                         \
      *reinterpret_cast<u64*>(&SH0[(H0W) * 2176 + ln * 136 + fme]) =            \
          pk4(h0s[0], h0s[1], h0s[2], h0s[3]);                                  \
    }                                                                           \
    {                                                                           \
      _Pragma("unroll")                                                         \
      for (int j = 0; j < 4; ++j) {                                             \
        float r = sigm(dR[j]);                                                  \
        float z = sigm(dZ[j]);                                                  \
        float n = tanhg(fmaf(r, dHN[j], dIN[j]));                               \
        h1s[j] = fmaf(z, h1s[j] - n, n);                                        \
      }                                                                         \
      u64 q = pk4(h1s[0], h1s[1], h1s[2], h1s[3]);                              \
      *reinterpret_cast<u64*>(&SH1[(H0R) * 2176 + ln * 136 + fme]) = q;         \
      if (SLOT_OK) {                                                            \
        hp += (size_t)B_ * H_;                                                  \
        *reinterpret_cast<u64*>(hp) = q;                                        \
      }                                                                         \
    }                                                                           \
    if (PF) {                                                                   \
      gq0 = *reinterpret_cast<const u64*>(gp);                                  \
      gq1 = *reinterpret_cast<const u64*>(gp + 128);                            \
      gq2 = *reinterpret_cast<const u64*>(gp + 256);                            \
      gp += (size_t)B_ * 384;                                                   \
    }                                                                           \
    bar_lds();                                                                  \
  }

  for (int s = 1; s <= TCr; s += 2) {
    // period s (odd): H0 read parity 0, write parity 1; H1 read parity 1, write parity 0
    GRU_PERIOD(0, 1, true, true, (s + 1 < TCr))
    // period s+1 (even): parities flipped; L0 only if s+1 < TCr
    GRU_PERIOD(1, 0, (s + 1 < TCr), (s + 1 < TCr), (s + 2 < TCr))
  }
#undef GRU_PERIOD

#pragma unroll
  for (int j = 0; j < 4; ++j) {
    hst[(size_t)(0 * B_ + b0 + ln) * H_ + fme + j] = h0s[j];
    hst[(size_t)(1 * B_ + b0 + ln) * H_ + fme + j] = h1s[j];
  }
}

// ===================== ROLE: post-chain (8 waves x 32 rows) =====================
DI void layer128(const u16* __restrict__ W, const float* __restrict__ bias,
                 const u16* A, u16* Dst, int dstOff, int nTiles, bool relu,
                 int ln, int lq) {
  bf16v a[2][4];
#pragma unroll
  for (int mt = 0; mt < 2; ++mt)
#pragma unroll
    for (int kt = 0; kt < 4; ++kt)
      a[mt][kt] = ldb(A + (mt * 16 + ln) * 136 + kt * 32 + lq * 8);
  for (int nt = 0; nt < nTiles; ++nt) {
    f32x4 c0 = {0,0,0,0}, c1 = {0,0,0,0};
#pragma unroll
    for (int kt = 0; kt < 4; ++kt) {
      bf16v b = ldb(W + (nt * 16 + ln) * 128 + kt * 32 + lq * 8);
      c0 = MFMA(a[0][kt], b, c0); c1 = MFMA(a[1][kt], b, c1);
    }
    float bv = bias[nt * 16 + ln];
#pragma unroll
    for (int mt = 0; mt < 2; ++mt)
#pragma unroll
      for (int j = 0; j < 4; ++j) {
        float v = (mt ? c1[j] : c0[j]) + bv;
        if (relu) v = fmaxf(v, 0.f);
        Dst[(mt * 16 + lq * 4 + j) * 136 + dstOff + nt * 16 + ln] = f2b(v);
      }
  }
}

DI void role_post(u16* smem, const u16* __restrict__ phiu, const u16* __restrict__ h1old,
                  const u16* __restrict__ yT, const u16* __restrict__ wb,
                  const float* dy_b1, const float* dy_b2, const float* xm_b,
                  const float* xlv_b, const float* px_b1, const float* px_b2,
                  const float* me_b1, const float* me_b2,
                  float* __restrict__ partials, int first, int blk) {
  const int lane = threadIdx.x & 63, w = threadIdx.x >> 6;   // 8 waves
  const int ln = lane & 15, lq = lane >> 4;
  const int r0 = (blk * 8 + w) * 32;
  u16* X = smem + w * 8704;
  u16* Yb = X + 4352;
  float* wsum = (float*)(smem + 69632);

  {
    bf16v a[2][8];
#pragma unroll
    for (int mt = 0; mt < 2; ++mt)
#pragma unroll
      for (int kt = 0; kt < 8; ++kt) {
        size_t row = (size_t)(r0 + mt * 16 + ln);
        a[mt][kt] = (kt < 4) ? ldb(phiu + row * H_ + kt * 32 + lq * 8)
                             : ldb(h1old + row * H_ + (kt - 4) * 32 + lq * 8);
      }
    const u16* W = wb + O_DY_W1;
    for (int nt = 0; nt < 8; ++nt) {
      f32x4 c0 = {0,0,0,0}, c1 = {0,0,0,0};
#pragma unroll
      for (int kt = 0; kt < 8; ++kt) {
        bf16v b = ldb(W + (nt * 16 + ln) * 256 + kt * 32 + lq * 8);
        c0 = MFMA(a[0][kt], b, c0); c1 = MFMA(a[1][kt], b, c1);
      }
      float bv = dy_b1[nt * 16 + ln];
#pragma unroll
      for (int mt = 0; mt < 2; ++mt)
#pragma unroll
        for (int j = 0; j < 4; ++j) {
          float v = (mt ? c1[j] : c0[j]) + bv;
          X[(mt * 16 + lq * 4 + j) * 136 + nt * 16 + ln] = f2b(fmaxf(v, 0.f));
        }
    }
  }
  layer128(wb + O_DY_W2, dy_b2, X, Yb, 0, 8, false, ln, lq);
  layer128(wb + O_XM_W,  xm_b,  Yb, X, 0, 4, false, ln, lq);
  layer128(wb + O_XLV_W, xlv_b, Yb, X, 64, 4, false, ln, lq);
  layer128(wb + O_PX_W1, px_b1, X, Yb, 0, 8, true,  ln, lq);
  layer128(wb + O_PX_W2, px_b2, Yb, X, 0, 8, false, ln, lq);
  layer128(wb + O_ME_W1, me_b1, X, Yb, 0, 8, true,  ln, lq);

  float lsum = 0.f;
  {
    bf16v a[2][4];
#pragma unroll
    for (int mt = 0; mt < 2; ++mt)
#pragma unroll
      for (int kt = 0; kt < 4; ++kt)
        a[mt][kt] = ldb(Yb + (mt * 16 + ln) * 136 + kt * 32 + lq * 8);
    const u16* W = wb + O_ME_W2;
#pragma unroll
    for (int nt = 0; nt < 2; ++nt) {
      f32x4 c0 = {0,0,0,0}, c1 = {0,0,0,0};
#pragma unroll
      for (int kt = 0; kt < 4; ++kt) {
        bf16v b = ldb(W + (nt * 16 + ln) * 128 + kt * 32 + lq * 8);
        c0 = MFMA(a[0][kt], b, c0); c1 = MFMA(a[1][kt], b, c1);
      }
      float bv = me_b2[nt * 16 + ln];
#pragma unroll
      for (int mt = 0; mt < 2; ++mt)
#pragma unroll
        for (int j = 0; j < 4; ++j) {
          int m = mt * 16 + lq * 4 + j;
          float v = (mt ? c1[j] : c0[j]) + bv;
          float yv = b2f(yT[(size_t)(r0 + m) * 32 + nt * 16 + ln]);
          float d = v - yv;
          lsum += d * d;
        }
    }
  }
#pragma unroll
  for (int o = 32; o; o >>= 1) lsum += __shfl_down(lsum, o);
  if (lane == 0) wsum[w] = lsum;
  __syncthreads();
  if (threadIdx.x == 0) {
    float v = 0.f;
#pragma unroll
    for (int i = 0; i < 8; ++i) v += wsum[i];
    if (first) partials[blk] = v;
    else       partials[blk] += v;
  }
}

// ===================== ROLE: phi_u + gi0 (8 waves x 32 rows) ====================
DI void role_phiu(u16* smem, const u16* __restrict__ uT, const u16* __restrict__ wb,
                  const float* __restrict__ pu_b1, const float* __restrict__ pu_b2,
                  u16* __restrict__ phiu, u16* __restrict__ gi0, int blk) {
  const int lane = threadIdx.x & 63, w = threadIdx.x >> 6;   // 8 waves
  const int ln = lane & 15, lq = lane >> 4;
  const int r0 = (blk * 8 + w) * 32;
  u16* hb  = smem + w * 4352;
  u16* hb2 = smem + 34816 + w * 4352;

  bf16v a0 = ldb(uT + (size_t)(r0 + ln) * 32 + lq * 8);
  bf16v a1 = ldb(uT + (size_t)(r0 + 16 + ln) * 32 + lq * 8);
  const u16* w1 = wb + O_PU_W1;
#pragma unroll
  for (int nt = 0; nt < 8; ++nt) {
    f32x4 c0 = {0.f, 0.f, 0.f, 0.f}, c1 = {0.f, 0.f, 0.f, 0.f};
    bf16v b = ldb(w1 + (nt * 16 + ln) * 32 + lq * 8);
    c0 = MFMA(a0, b, c0); c1 = MFMA(a1, b, c1);
    float bv = pu_b1[nt * 16 + ln];
#pragma unroll
    for (int j = 0; j < 4; ++j) {
      hb[(lq * 4 + j) * 136 + nt * 16 + ln]      = f2b(fmaxf(c0[j] + bv, 0.f));
      hb[(16 + lq * 4 + j) * 136 + nt * 16 + ln] = f2b(fmaxf(c1[j] + bv, 0.f));
    }
  }
  bf16v a[2][4];
#pragma unroll
  for (int mt = 0; mt < 2; ++mt)
#pragma unroll
    for (int kt = 0; kt < 4; ++kt)
      a[mt][kt] = ldb(hb + (mt * 16 + ln) * 136 + kt * 32 + lq * 8);
  const u16* w2 = wb + O_PU_W2;
#pragma unroll
  for (int nt = 0; nt < 8; ++nt) {
    f32x4 c0 = {0.f, 0.f, 0.f, 0.f}, c1 = {0.f, 0.f, 0.f, 0.f};
#pragma unroll
    for (int kt = 0; kt < 4; ++kt) {
      bf16v b = ldb(w2 + (nt * 16 + ln) * 128 + kt * 32 + lq * 8);
      c0 = MFMA(a[0][kt], b, c0); c1 = MFMA(a[1][kt], b, c1);
    }
    float bv = pu_b2[nt * 16 + ln];
#pragma unroll
    for (int mt = 0; mt < 2; ++mt)
#pragma unroll
      for (int j = 0; j < 4; ++j) {
        float v = (mt ? c1[j] : c0[j]) + bv;
        hb2[(mt * 16 + lq * 4 + j) * 136 + nt * 16 + ln] = f2b(v);
      }
  }
  __syncthreads();

#pragma unroll
  for (int i = 0; i < 16; ++i) {
    int idx = lane + 64 * i;
    int row = idx >> 5, c4 = idx & 31;
    u64 v = *reinterpret_cast<const u64*>(&hb2[row * 136 + c4 * 4]);
    *reinterpret_cast<u64*>(&phiu[(size_t)(r0 + row) * 128 + c4 * 4]) = v;
  }

  bf16v bP[2][4];
#pragma unroll
  for (int bh = 0; bh < 2; ++bh)
#pragma unroll
    for (int kt = 0; kt < 4; ++kt)
      bP[bh][kt] = ldb(&hb2[(bh * 16 + ln) * 136 + kt * 32 + lq * 8]);
  const u16* wih0 = wb + O_WIH;
  for (int nt = 0; nt < 24; ++nt) {
    bf16v aW[4];
#pragma unroll
    for (int kt = 0; kt < 4; ++kt)
      aW[kt] = ldb(wih0 + (size_t)(nt * 16 + ln) * 128 + kt * 32 + lq * 8);
#pragma unroll
    for (int bh = 0; bh < 2; ++bh) {
      f32x4 c = {0.f, 0.f, 0.f, 0.f};
#pragma unroll
      for (int kt = 0; kt < 4; ++kt) c = MFMA(aW[kt], bP[bh][kt], c);
      u64 q = pk4(c[0], c[1], c[2], c[3]);
      *reinterpret_cast<u64*>(
          &gi0[(size_t)(r0 + bh * 16 + ln) * 384 + nt * 16 + lq * 4]) = q;
    }
  }
}

// ===================== ROLE: transpose (2 workers x 4 tiles) ====================
DI void role_transpose(u16* smem, const float* __restrict__ u, const float* __restrict__ y,
                       u16* __restrict__ uT, u16* __restrict__ yT, int t0, int blk, int TCr) {
  float* tile = (float*)smem;                 // [2][32*33]
  const int worker = threadIdx.x >> 8;        // 0..1
  const int tid = threadIdx.x & 255;
  const int tx = tid & 31, ty = tid >> 5;     // 32 x 8
  float* tl = tile + worker * (32 * 33);
  const int ntt = TCr / 32;
  for (int i = 0; i < 4; ++i) {
    int gtile = blk * 8 + worker * 4 + i;
    int tt = gtile % ntt;
    int rest = gtile / ntt;
    int rr = rest & 255, uy = rest >> 8;
    const float* src = uy ? y : u;
    u16* dst = uy ? yT : uT;
    int c0 = tt * 32, r0 = rr * 32;
#pragma unroll
    for (int k = 0; k < 4; ++k)
      tl[(ty + k * 8) * 33 + tx] = src[(size_t)(r0 + ty + k * 8) * T_ + t0 + c0 + tx];
    __syncthreads();
#pragma unroll
    for (int k = 0; k < 4; ++k)
      dst[(size_t)(c0 + ty + k * 8) * BU + r0 + tx] = f2b(tl[tx * 33 + ty + k * 8]);
    __syncthreads();
  }
}

// ===================== MEGA kernel: role dispatch by blockIdx ===================
__global__ __launch_bounds__(512, 2) void k_mega(
    const float* u, const float* yy,
    const u16* uT_r, u16* uT_w, u16* yT_w, const u16* yT_r,
    const u16* phiu_r, u16* phiu_w,
    const u16* gi0_r, u16* gi0_w,
    const u16* h1_r, u16* h1_w,
    const u16* wb, float* hst,
    const float* pu_b1, const float* pu_b2,
    const float* dy_b1, const float* dy_b2, const float* xm_b, const float* xlv_b,
    const float* px_b1, const float* px_b2, const float* me_b1, const float* me_b2,
    float* partials, int first,
    int TCr, int nG, int nP, int nU, int t0T) {
  __shared__ __align__(16) u16 smem[69664];   // 139,328 B: max over roles
  int b = blockIdx.x;
  if (b < nG) { role_gru(smem, gi0_r, wb, hst, h1_w, TCr, b); return; }
  b -= nG;
  if (b < nP) {
    role_post(smem, phiu_r, h1_r, yT_r, wb, dy_b1, dy_b2, xm_b, xlv_b,
              px_b1, px_b2, me_b1, me_b2, partials, first, b);
    return;
  }
  b -= nP;
  if (b < nU) { role_phiu(smem, uT_r, wb, pu_b1, pu_b2, phiu_w, gi0_w, b); return; }
  b -= nU;
  role_transpose(smem, u, yy, uT_w, yT_w, t0T, b, TCr);
}

// ============ finalize ============
__global__ void k_finalize(const float* __restrict__ partials, float* __restrict__ out,
                           int nPart) {
  __shared__ double s[256];
  double acc = 0.0;
  for (int i = threadIdx.x; i < nPart; i += 256) acc += (double)partials[i];
  s[threadIdx.x] = acc;
  __syncthreads();
  for (int o = 128; o; o >>= 1) {
    if (threadIdx.x < o) s[threadIdx.x] += s[threadIdx.x + o];
    __syncthreads();
  }
  if (threadIdx.x == 0) out[0] = (float)s[0];
}

extern "C" void kernel_launch(void* const* d_in, const int* in_sizes, int n_in,
                              void* d_out, int out_size, void* d_ws, size_t ws_size,
                              hipStream_t stream) {
  const float* u     = (const float*)d_in[0];
  const float* y     = (const float*)d_in[1];
  const float* h0    = (const float*)d_in[2];
  const float* pu_w1 = (const float*)d_in[3];
  const float* pu_b1 = (const float*)d_in[4];
  const float* pu_w2 = (const float*)d_in[5];
  const float* pu_b2 = (const float*)d_in[6];
  const float* dy_w1 = (const float*)d_in[7];
  const float* dy_b1 = (const float*)d_in[8];
  const float* dy_w2 = (const float*)d_in[9];
  const float* dy_b2 = (const float*)d_in[10];
  const float* xm_w  = (const float*)d_in[11];
  const float* xm_b  = (const float*)d_in[12];
  const float* xlv_w = (const float*)d_in[13];
  const float* xlv_b = (const float*)d_in[14];
  const float* px_w1 = (const float*)d_in[15];
  const float* px_b1 = (const float*)d_in[16];
  const float* px_w2 = (const float*)d_in[17];
  const float* px_b2 = (const float*)d_in[18];
  const float* me_w1 = (const float*)d_in[19];
  const float* me_b1 = (const float*)d_in[20];
  const float* me_w2 = (const float*)d_in[21];
  const float* me_b2 = (const float*)d_in[22];
  const float* gih   = (const float*)d_in[23];
  const float* ghh   = (const float*)d_in[24];

  // time-chunk tier vs workspace (ring buffers: uT x2, yT x4, phiu x3, h1 x2, gi0 x2)
  int TC = 64;
  for (int cand : {256, 128}) {
    size_t ut = (size_t)cand * B_ * 32 * 2;
    size_t ph = (size_t)cand * B_ * 128 * 2;
    size_t gi = (size_t)cand * B_ * 384 * 2;
    if (WS_DATA + 6 * ut + 5 * ph + 2 * gi <= ws_size) { TC = cand; break; }
  }
  const int NCH = T_ / TC;
  const int RC = TC * B_;
  size_t ut_b = (size_t)RC * 32 * 2, ph_b = (size_t)RC * 128 * 2, gi_b = (size_t)RC * 384 * 2;

  char* ws = (char*)d_ws;
  u16* wb    = (u16*)(ws + WS_WB);
  float* hst = (float*)(ws + WS_HST);
  float* prt = (float*)(ws + WS_PART);
  char* p = ws + WS_DATA;
  u16* uTb[2]; u16* yTb[4]; u16* phb[3]; u16* h1b[2]; u16* gib[2];
  for (int i = 0; i < 2; ++i) { uTb[i] = (u16*)p; p += ut_b; }
  for (int i = 0; i < 4; ++i) { yTb[i] = (u16*)p; p += ut_b; }
  for (int i = 0; i < 3; ++i) { phb[i] = (u16*)p; p += ph_b; }
  for (int i = 0; i < 2; ++i) { h1b[i] = (u16*)p; p += ph_b; }
  for (int i = 0; i < 2; ++i) { gib[i] = (u16*)p; p += gi_b; }
  float* out = (float*)d_out;

  const int nPostB = RC / 256;            // post blocks per chunk
  const int nPhiB  = RC / 256;            // phi_u blocks per chunk
  const int nTrB   = (TC / 32) * 64;      // transpose blocks per chunk (tiles/8)

  k_convert_weights<<<256, 256, 0, stream>>>(pu_w1, pu_w2, dy_w1, dy_w2, xm_w, xlv_w,
                                             px_w1, px_w2, me_w1, me_w2, gih, ghh,
                                             h0, wb, hst);
  // prologue: transpose chunks 0,1 ; phi_u chunk 0
  k_transpose<<<dim3(TC / 32, 256, 2), dim3(32, 8), 0, stream>>>(u, y, uTb[0], yTb[0], 0);
  if (NCH > 1)
    k_transpose<<<dim3(TC / 32, 256, 2), dim3(32, 8), 0, stream>>>(u, y, uTb[1], yTb[1], TC);
  k_mega<<<nPhiB, 512, 0, stream>>>(u, y, uTb[0], uTb[0], yTb[0], yTb[0],
                                    phb[0], phb[0], gib[0], gib[0], h1b[0], h1b[0],
                                    wb, hst, pu_b1, pu_b2, dy_b1, dy_b2, xm_b, xlv_b,
                                    px_b1, px_b2, me_b1, me_b2, prt, 0,
                                    TC, 0, 0, nPhiB, 0);
  // main pipeline: mega(c) = GRU(c) || post(c-1) || phi_u(c+1) || transpose(c+2)
  for (int c = 0; c <= NCH; ++c) {
    int nG = (c < NCH) ? 16 : 0;
    int nP = (c >= 1) ? nPostB : 0;
    int nU = (c + 1 < NCH) ? nPhiB : 0;
    int nT = (c + 2 < NCH) ? nTrB : 0;
    int grid = nG + nP + nU + nT;
    if (!grid) continue;
    k_mega<<<grid, 512, 0, stream>>>(
        u, y,
        uTb[(c + 1) & 1], uTb[(c + 2) & 1], yTb[(c + 2) & 3],
        yTb[c >= 1 ? (c - 1) & 3 : 0],
        phb[c >= 1 ? (c - 1) % 3 : 0], phb[(c + 1) % 3],
        gib[c & 1], gib[(c + 1) & 1],
        h1b[c >= 1 ? (c - 1) & 1 : 0], h1b[c & 1],
        wb, hst, pu_b1, pu_b2, dy_b1, dy_b2, xm_b, xlv_b,
        px_b1, px_b2, me_b1, me_b2,
        prt, (c == 1) ? 1 : 0,
        TC, nG, nP, nU, (c + 2) * TC);
  }
  k_finalize<<<1, 256, 0, stream>>>(prt, out, nPostB);
}